// Round 4
// baseline (1123.152 us; speedup 1.0000x reference)
//
#include <hip/hip_runtime.h>
#include <cstdint>
#include <cstddef>

#define NN 100000
#define NE 1600000
#define IND 128
#define OUTD 64
#define MDIM 16
#define GHID 64

// ---------------- edge-index dtype detection (int32 vs int64) --------------
__global__ __launch_bounds__(64) void k_detect(const void* ei, int* flag) {
    const unsigned long long* p = (const unsigned long long*)ei;
    int i = threadIdx.x;
    unsigned long long v = p[(size_t)i * (NE / 64)];
    bool hi0 = (v >> 32) == 0ull;
    unsigned long long b = __ballot(hi0);
    if (i == 0) *flag = (b == ~0ull) ? 1 : 0;  // all high dwords zero -> int64
}

__global__ __launch_bounds__(256) void k_convert(const void* ei, const int* flag,
                                                 int* idx32) {
    int i = blockIdx.x * 256 + threadIdx.x;
    if (i >= 2 * NE) return;
    if (*flag)
        idx32[i] = (int)((const long long*)ei)[i];
    else
        idx32[i] = ((const int*)ei)[i];
}

__global__ __launch_bounds__(256) void k_init(int* count) {
    int n = blockIdx.x * 256 + threadIdx.x;
    if (n < NN) count[n] = 0;
}

// ---------------- dst histogram (int atomics only, tiny kernel) ------------
__global__ __launch_bounds__(256) void k_hist(const int* __restrict__ dst,
                                              int* __restrict__ count) {
    int e = blockIdx.x * 256 + threadIdx.x;
    if (e < NE) atomicAdd(&count[dst[e]], 1);
}

// ---------------- Pa/Pb precompute: Pab[n][0:64]=motif@W1a, [64:128]=@W1b --
// 4 threads per node, each computes a 32-col chunk of the 128-wide row
__global__ __launch_bounds__(256) void k_pre(const float* __restrict__ motif,
                                             const float* __restrict__ w1,
                                             float* __restrict__ Pab) {
    int idx = blockIdx.x * 256 + threadIdx.x;
    int n = idx >> 2, q = idx & 3;
    if (n >= NN) return;
    float m[MDIM];
    const float4* mr = (const float4*)(motif + (size_t)n * MDIM);
#pragma unroll
    for (int i = 0; i < 4; i++) {
        float4 t = mr[i];
        m[4 * i] = t.x; m[4 * i + 1] = t.y; m[4 * i + 2] = t.z; m[4 * i + 3] = t.w;
    }
    const float* wbase = (q < 2) ? (w1 + q * 32) : (w1 + MDIM * GHID + (q - 2) * 32);
    float h[32];
#pragma unroll
    for (int j = 0; j < 32; j++) h[j] = 0.0f;
#pragma unroll 1
    for (int k = 0; k < MDIM; k++) {
        float f = m[k];
        const float* w = wbase + k * GHID;
#pragma unroll
        for (int j = 0; j < 32; j++) h[j] = fmaf(f, w[j], h[j]);
    }
    float* op = Pab + (size_t)n * 128 + q * 32;
#pragma unroll
    for (int j4 = 0; j4 < 8; j4++)
        *(float4*)(op + 4 * j4) =
            make_float4(h[4 * j4], h[4 * j4 + 1], h[4 * j4 + 2], h[4 * j4 + 3]);
}

// ---------------- edge gate MLP: no atomics, half the FLOPs ----------------
// h = Pa[s] + Pb[d] + b1 + |mu-mv|@W1c + (mu*mv)@W1d  (2048 MAC/edge)
__global__ __launch_bounds__(256, 4) void k_gate(
    const float* __restrict__ motif, const int* __restrict__ src,
    const int* __restrict__ dst, const float* __restrict__ Pab,
    const float* __restrict__ w1, const float* __restrict__ b1,
    const float* __restrict__ w2, const float* __restrict__ b2,
    float* __restrict__ gate) {
    int e = blockIdx.x * 256 + threadIdx.x;
    if (e >= NE) return;
    int s = src[e], d = dst[e];
    float mu[MDIM], mv[MDIM];
    const float4* ms = (const float4*)(motif + (size_t)s * MDIM);
    const float4* mdp = (const float4*)(motif + (size_t)d * MDIM);
#pragma unroll
    for (int q = 0; q < 4; q++) {
        float4 a = ms[q], b = mdp[q];
        mu[4 * q] = a.x; mu[4 * q + 1] = a.y; mu[4 * q + 2] = a.z; mu[4 * q + 3] = a.w;
        mv[4 * q] = b.x; mv[4 * q + 1] = b.y; mv[4 * q + 2] = b.z; mv[4 * q + 3] = b.w;
    }
    const float4* pas = (const float4*)(Pab + (size_t)s * 128);
    const float4* pbd = (const float4*)(Pab + (size_t)d * 128 + 64);
    const float* w1c = w1 + 2 * MDIM * GHID;
    const float* w1d = w1 + 3 * MDIM * GHID;
    float g = b2[0];
#pragma unroll 1
    for (int jh = 0; jh < 2; jh++) {
        float h[32];
#pragma unroll
        for (int j4 = 0; j4 < 8; j4++) {
            float4 a = pas[jh * 8 + j4];
            float4 b = pbd[jh * 8 + j4];
            const float4 bb = *(const float4*)(b1 + jh * 32 + 4 * j4);
            h[4 * j4] = a.x + b.x + bb.x;
            h[4 * j4 + 1] = a.y + b.y + bb.y;
            h[4 * j4 + 2] = a.z + b.z + bb.z;
            h[4 * j4 + 3] = a.w + b.w + bb.w;
        }
#pragma unroll 1
        for (int k = 0; k < MDIM; k++) {
            float f0 = mu[k], f1 = mv[k];
            float f2 = fabsf(f0 - f1), f3 = f0 * f1;
            const float* wc = w1c + k * GHID + jh * 32;
            const float* wd = w1d + k * GHID + jh * 32;
#pragma unroll
            for (int j = 0; j < 32; j++) {
                h[j] = fmaf(f2, wc[j], h[j]);
                h[j] = fmaf(f3, wd[j], h[j]);
            }
        }
        const float* w2p = w2 + jh * 32;
#pragma unroll
        for (int j = 0; j < 32; j++) g = fmaf(fmaxf(h[j], 0.0f), w2p[j], g);
    }
    gate[e] = 1.0f / (1.0f + __expf(-g));
}

// ---------------- counting-sort scan (exclusive prefix of count) -----------
__global__ __launch_bounds__(256) void k_scan1(const int* __restrict__ count,
                                               int* __restrict__ rs,
                                               int* __restrict__ bsum) {
    __shared__ int sd[256];
    int tid = threadIdx.x;
    int base = blockIdx.x * 2048 + tid * 8;
    int loc[8]; int s = 0;
#pragma unroll
    for (int i = 0; i < 8; i++) {
        int idx = base + i;
        int v = (idx < NN) ? count[idx] : 0;
        loc[i] = s; s += v;
    }
    sd[tid] = s; __syncthreads();
    for (int off = 1; off < 256; off <<= 1) {
        int t = (tid >= off) ? sd[tid - off] : 0;
        __syncthreads();
        sd[tid] += t;
        __syncthreads();
    }
    int texcl = sd[tid] - s;
    if (tid == 255) bsum[blockIdx.x] = sd[255];
#pragma unroll
    for (int i = 0; i < 8; i++) {
        int idx = base + i;
        if (idx < NN) rs[idx] = texcl + loc[i];
    }
}

__global__ __launch_bounds__(64) void k_scan2(const int* __restrict__ bsum,
                                              int* __restrict__ boffs) {
    int tid = threadIdx.x;
    int v = (tid < 49) ? bsum[tid] : 0;
    int x = v;
#pragma unroll
    for (int off = 1; off < 64; off <<= 1) {
        int t = __shfl_up(x, off, 64);
        if (tid >= off) x += t;
    }
    boffs[tid] = x - v;  // exclusive
}

__global__ __launch_bounds__(256) void k_scan3(int* __restrict__ rs,
                                               const int* __restrict__ boffs,
                                               int* __restrict__ cursor) {
    int i = blockIdx.x * 256 + threadIdx.x;
    if (i < NN) {
        int v = rs[i] + boffs[i >> 11];
        rs[i] = v;
        cursor[i] = v;
    }
}

// ---------------- fill CSR: src + raw gate, sorted by dst ------------------
__global__ __launch_bounds__(256) void k_fill(
    const int* __restrict__ src, const int* __restrict__ dst,
    const float* __restrict__ gate, int* __restrict__ cursor,
    int* __restrict__ src_s, float* __restrict__ g_s) {
    int e = blockIdx.x * 256 + threadIdx.x;
    if (e >= NE) return;
    int d = dst[e];
    int pos = atomicAdd(&cursor[d], 1);
    src_s[pos] = src[e];
    g_s[pos] = gate[e];
}

// ---------------- deg = 1 + row-sum of sorted gates -> dinv ----------------
__global__ __launch_bounds__(256) void k_deg(const int* __restrict__ rowstart,
                                             const int* __restrict__ count,
                                             const float* __restrict__ g_s,
                                             float* __restrict__ dinv) {
    int n = blockIdx.x * 256 + threadIdx.x;
    if (n >= NN) return;
    int a = rowstart[n], cnt = count[n];
    float sum = 1.0f;
    for (int i = 0; i < cnt; i++) sum += g_s[a + i];
    dinv[n] = rsqrtf(sum);
}

// ---------------- w_s[i] = dinv[src]*gate*dinv[row] ------------------------
__global__ __launch_bounds__(256) void k_wnorm(
    const int* __restrict__ rowstart, const int* __restrict__ count,
    const int* __restrict__ src_s, const float* __restrict__ g_s,
    const float* __restrict__ dinv, float* __restrict__ w_s) {
    int n = blockIdx.x * 256 + threadIdx.x;
    if (n >= NN) return;
    int a = rowstart[n], cnt = count[n];
    float dn = dinv[n];
    for (int i = 0; i < cnt; i++)
        w_s[a + i] = dinv[src_s[a + i]] * g_s[a + i] * dn;
}

// ---------------- xw = A @ W (128x128) -------------------------------------
__global__ __launch_bounds__(256) void k_conv_gemm(
    const float* __restrict__ A, const float* __restrict__ Bw,
    float* __restrict__ xw) {
    __shared__ float sB[IND * IND];  // 64 KB
    int tid = threadIdx.x;
    {
        const float4* B4 = (const float4*)Bw;
        float4* s4 = (float4*)sB;
#pragma unroll
        for (int i = 0; i < 16; i++) s4[tid + 256 * i] = B4[tid + 256 * i];
    }
    __syncthreads();
    int cg = tid >> 5, rs = tid & 31;
    int row0 = blockIdx.x * 128 + rs * 4;
    int col0 = cg * 16;
    float acc[4][16];
#pragma unroll
    for (int j = 0; j < 4; j++)
#pragma unroll
        for (int c = 0; c < 16; c++) acc[j][c] = 0.0f;
    for (int k = 0; k < IND; k += 4) {
        float4 a[4];
#pragma unroll
        for (int j = 0; j < 4; j++) {
            int r = row0 + j;
            a[j] = (r < NN) ? *(const float4*)(A + (size_t)r * IND + k)
                            : make_float4(0.f, 0.f, 0.f, 0.f);
        }
#pragma unroll
        for (int kk = 0; kk < 4; kk++) {
            float b[16];
            const float4* bb = (const float4*)(sB + (k + kk) * IND + col0);
#pragma unroll
            for (int q = 0; q < 4; q++) {
                float4 t = bb[q];
                b[4 * q] = t.x; b[4 * q + 1] = t.y; b[4 * q + 2] = t.z; b[4 * q + 3] = t.w;
            }
#pragma unroll
            for (int j = 0; j < 4; j++) {
                float av = (kk == 0) ? a[j].x : (kk == 1) ? a[j].y : (kk == 2) ? a[j].z : a[j].w;
#pragma unroll
                for (int c = 0; c < 16; c++) acc[j][c] = fmaf(av, b[c], acc[j][c]);
            }
        }
    }
#pragma unroll
    for (int j = 0; j < 4; j++) {
        int r = row0 + j;
        if (r >= NN) continue;
        float* xo = xw + (size_t)r * IND + col0;
#pragma unroll
        for (int q = 0; q < 4; q++)
            *(float4*)(xo + 4 * q) =
                make_float4(acc[j][4 * q], acc[j][4 * q + 1], acc[j][4 * q + 2],
                            acc[j][4 * q + 3]);
    }
}

// ---------------- fused gather + bias + LN + relu + residual ---------------
__global__ __launch_bounds__(256) void k_aggr(
    const int* __restrict__ rowstart, const int* __restrict__ count,
    const int* __restrict__ src_s, const float* __restrict__ w_s,
    const float* __restrict__ xw, const float* __restrict__ dinv,
    const float* __restrict__ xold, float* __restrict__ xnew,
    const float* __restrict__ cb, const float* __restrict__ lg,
    const float* __restrict__ lb) {
    int n = blockIdx.x * 4 + (threadIdx.x >> 6);
    int lane = threadIdx.x & 63;
    if (n >= NN) return;
    const float2* xw2 = (const float2*)xw;
    float dn = dinv[n];
    float2 acc = xw2[(size_t)n * 64 + lane];  // self-loop: dinv[n]^2 * xw[n]
    acc.x *= dn * dn; acc.y *= dn * dn;
    int start = rowstart[n], cnt = count[n];
    for (int c = 0; c < cnt; c += 64) {
        int rem = cnt - c;
        int sv = 0; float wv = 0.0f;
        if (lane < rem) {
            sv = src_s[start + c + lane];
            wv = w_s[start + c + lane];
        }
        int m = rem < 64 ? rem : 64;
        int j = 0;
        for (; j + 4 <= m; j += 4) {  // 4 independent loads in flight
            int s0 = __shfl(sv, j, 64), s1 = __shfl(sv, j + 1, 64);
            int s2 = __shfl(sv, j + 2, 64), s3 = __shfl(sv, j + 3, 64);
            float w0 = __shfl(wv, j, 64), w1 = __shfl(wv, j + 1, 64);
            float w2 = __shfl(wv, j + 2, 64), w3 = __shfl(wv, j + 3, 64);
            float2 v0 = xw2[(size_t)s0 * 64 + lane];
            float2 v1 = xw2[(size_t)s1 * 64 + lane];
            float2 v2 = xw2[(size_t)s2 * 64 + lane];
            float2 v3 = xw2[(size_t)s3 * 64 + lane];
            acc.x = fmaf(w0, v0.x, acc.x); acc.y = fmaf(w0, v0.y, acc.y);
            acc.x = fmaf(w1, v1.x, acc.x); acc.y = fmaf(w1, v1.y, acc.y);
            acc.x = fmaf(w2, v2.x, acc.x); acc.y = fmaf(w2, v2.y, acc.y);
            acc.x = fmaf(w3, v3.x, acc.x); acc.y = fmaf(w3, v3.y, acc.y);
        }
        for (; j < m; j++) {
            int s = __shfl(sv, j, 64);
            float w = __shfl(wv, j, 64);
            float2 v = xw2[(size_t)s * 64 + lane];
            acc.x = fmaf(w, v.x, acc.x); acc.y = fmaf(w, v.y, acc.y);
        }
    }
    float2 cbv = ((const float2*)cb)[lane];
    acc.x += cbv.x; acc.y += cbv.y;
    float s1 = acc.x + acc.y, s2 = acc.x * acc.x + acc.y * acc.y;
#pragma unroll
    for (int mm = 1; mm < 64; mm <<= 1) {
        s1 += __shfl_xor(s1, mm, 64);
        s2 += __shfl_xor(s2, mm, 64);
    }
    float mean = s1 * (1.0f / 128.0f);
    float var = s2 * (1.0f / 128.0f) - mean * mean;
    float rstd = rsqrtf(var + 1e-5f);
    float2 lgv = ((const float2*)lg)[lane];
    float2 lbv = ((const float2*)lb)[lane];
    float y0 = fmaxf((acc.x - mean) * rstd * lgv.x + lbv.x, 0.0f);
    float y1 = fmaxf((acc.y - mean) * rstd * lgv.y + lbv.y, 0.0f);
    float2 xo = ((const float2*)xold)[(size_t)n * 64 + lane];
    ((float2*)xnew)[(size_t)n * 64 + lane] =
        make_float2(xo.x + y0, xo.y + y1);
}

// ---------------- head: out = A @ head_w + head_b --------------------------
__global__ __launch_bounds__(256) void k_head(
    const float* __restrict__ A, const float* __restrict__ Bw,
    const float* __restrict__ bias, float* __restrict__ out) {
    __shared__ float sB[IND * OUTD];  // 32 KB
    int tid = threadIdx.x;
    {
        const float4* B4 = (const float4*)Bw;
        float4* s4 = (float4*)sB;
#pragma unroll
        for (int i = 0; i < 8; i++) s4[tid + 256 * i] = B4[tid + 256 * i];
    }
    __syncthreads();
    int cg = tid >> 6, rs = tid & 63;
    int row0 = blockIdx.x * 128 + rs * 2;
    int col0 = cg * 16;
    float acc[2][16];
#pragma unroll
    for (int j = 0; j < 2; j++)
#pragma unroll
        for (int c = 0; c < 16; c++) acc[j][c] = 0.0f;
    for (int k = 0; k < IND; k += 4) {
        float4 a[2];
#pragma unroll
        for (int j = 0; j < 2; j++) {
            int r = row0 + j;
            a[j] = (r < NN) ? *(const float4*)(A + (size_t)r * IND + k)
                            : make_float4(0.f, 0.f, 0.f, 0.f);
        }
#pragma unroll
        for (int kk = 0; kk < 4; kk++) {
            float b[16];
            const float4* bb = (const float4*)(sB + (k + kk) * OUTD + col0);
#pragma unroll
            for (int q = 0; q < 4; q++) {
                float4 t = bb[q];
                b[4 * q] = t.x; b[4 * q + 1] = t.y; b[4 * q + 2] = t.z; b[4 * q + 3] = t.w;
            }
#pragma unroll
            for (int j = 0; j < 2; j++) {
                float av = (kk == 0) ? a[j].x : (kk == 1) ? a[j].y : (kk == 2) ? a[j].z : a[j].w;
#pragma unroll
                for (int c = 0; c < 16; c++) acc[j][c] = fmaf(av, b[c], acc[j][c]);
            }
        }
    }
#pragma unroll
    for (int j = 0; j < 2; j++) {
        int r = row0 + j;
        if (r >= NN) continue;
        float* op = out + (size_t)r * OUTD + col0;
#pragma unroll
        for (int q = 0; q < 4; q++) {
            float4 bs = *(const float4*)(bias + col0 + 4 * q);
            *(float4*)(op + 4 * q) =
                make_float4(acc[j][4 * q] + bs.x, acc[j][4 * q + 1] + bs.y,
                            acc[j][4 * q + 2] + bs.z, acc[j][4 * q + 3] + bs.w);
        }
    }
}

extern "C" void kernel_launch(void* const* d_in, const int* in_sizes, int n_in,
                              void* d_out, int out_size, void* d_ws,
                              size_t ws_size, hipStream_t stream) {
    const float* x = (const float*)d_in[0];
    const float* motif = (const float*)d_in[1];
    const void* ei = d_in[2];
    const float* gw1 = (const float*)d_in[3];
    const float* gb1 = (const float*)d_in[4];
    const float* gw2 = (const float*)d_in[5];
    const float* gb2 = (const float*)d_in[6];
    const float* cw = (const float*)d_in[7];   // [2,128,128]
    const float* cb = (const float*)d_in[8];   // [2,128]
    const float* lg = (const float*)d_in[9];
    const float* lb = (const float*)d_in[10];
    const float* hw = (const float*)d_in[11];  // [128,64]
    const float* hb = (const float*)d_in[12];
    float* out = (float*)d_out;

    float* ws = (float*)d_ws;
    size_t o = 0;
    float* gate = ws + o; o += NE;          // aliased: w_s reuses this after fill
    float* dinv = ws + o; o += NN;
    int* idx32 = (int*)(ws + o); o += 2 * (size_t)NE;
    int* flag = (int*)(ws + o); o += 64;
    int* count = (int*)(ws + o); o += NN;
    int* rowstart = (int*)(ws + o); o += NN;
    int* cursor = (int*)(ws + o); o += NN;
    int* bsum = (int*)(ws + o); o += 64;
    int* boffs = (int*)(ws + o); o += 64;
    int* src_s = (int*)(ws + o); o += NE;
    float* g_s = ws + o; o += NE;
    float* xw = ws + o; o += (size_t)NN * IND;  // aliased with Pab (disjoint in time)
    float* xc = ws + o; o += (size_t)NN * IND;

    float* Pab = xw;   // alias: Pab dead before first k_conv_gemm writes xw
    float* w_s = gate; // alias: gate dead after k_fill; w_s written by k_wnorm

    const int* src = idx32;
    const int* dst = idx32 + NE;

    k_detect<<<1, 64, 0, stream>>>(ei, flag);
    k_convert<<<(2 * NE + 255) / 256, 256, 0, stream>>>(ei, flag, idx32);
    k_init<<<(NN + 255) / 256, 256, 0, stream>>>(count);
    k_hist<<<NE / 256, 256, 0, stream>>>(dst, count);
    k_pre<<<(4 * NN + 255) / 256, 256, 0, stream>>>(motif, gw1, Pab);
    k_gate<<<NE / 256, 256, 0, stream>>>(motif, src, dst, Pab, gw1, gb1, gw2,
                                         gb2, gate);

    // counting sort by dst -> CSR (shared by both layers)
    k_scan1<<<(NN + 2047) / 2048, 256, 0, stream>>>(count, rowstart, bsum);
    k_scan2<<<1, 64, 0, stream>>>(bsum, boffs);
    k_scan3<<<(NN + 255) / 256, 256, 0, stream>>>(rowstart, boffs, cursor);
    k_fill<<<NE / 256, 256, 0, stream>>>(src, dst, gate, cursor, src_s, g_s);
    k_deg<<<(NN + 255) / 256, 256, 0, stream>>>(rowstart, count, g_s, dinv);
    k_wnorm<<<(NN + 255) / 256, 256, 0, stream>>>(rowstart, count, src_s, g_s,
                                                  dinv, w_s);

    // layer 0
    k_conv_gemm<<<(NN + 127) / 128, 256, 0, stream>>>(x, cw, xw);
    k_aggr<<<(NN + 3) / 4, 256, 0, stream>>>(rowstart, count, src_s, w_s, xw,
                                             dinv, x, xc, cb, lg, lb);
    // layer 1
    k_conv_gemm<<<(NN + 127) / 128, 256, 0, stream>>>(xc, cw + IND * IND, xw);
    k_aggr<<<(NN + 3) / 4, 256, 0, stream>>>(rowstart, count, src_s, w_s, xw,
                                             dinv, xc, xc, cb + IND, lg + IND,
                                             lb + IND);

    k_head<<<(NN + 127) / 128, 256, 0, stream>>>(xc, hw, hb, out);
}

// Round 5
// 1047.530 us; speedup vs baseline: 1.0722x; 1.0722x over previous
//
#include <hip/hip_runtime.h>
#include <cstdint>
#include <cstddef>

#define NN 100000
#define NE 1600000
#define IND 128
#define OUTD 64
#define MDIM 16
#define GHID 64

// ---------------- edge-index dtype detection (int32 vs int64) --------------
__global__ __launch_bounds__(64) void k_detect(const void* ei, int* flag) {
    const unsigned long long* p = (const unsigned long long*)ei;
    int i = threadIdx.x;
    unsigned long long v = p[(size_t)i * (NE / 64)];
    bool hi0 = (v >> 32) == 0ull;
    unsigned long long b = __ballot(hi0);
    if (i == 0) *flag = (b == ~0ull) ? 1 : 0;  // all high dwords zero -> int64
}

__global__ __launch_bounds__(256) void k_convert(const void* ei, const int* flag,
                                                 int* idx32) {
    int i = blockIdx.x * 256 + threadIdx.x;
    if (i >= 2 * NE) return;
    if (*flag)
        idx32[i] = (int)((const long long*)ei)[i];
    else
        idx32[i] = ((const int*)ei)[i];
}

__global__ __launch_bounds__(256) void k_init(int* count) {
    int n = blockIdx.x * 256 + threadIdx.x;
    if (n < NN) count[n] = 0;
}

// ---------------- dst histogram (int atomics only, tiny kernel) ------------
__global__ __launch_bounds__(256) void k_hist(const int* __restrict__ dst,
                                              int* __restrict__ count) {
    int e = blockIdx.x * 256 + threadIdx.x;
    if (e < NE) atomicAdd(&count[dst[e]], 1);
}

// ---------------- Pa/Pb precompute: Pab[n][0:64]=motif@W1a, [64:128]=@W1b --
__global__ __launch_bounds__(256) void k_pre(const float* __restrict__ motif,
                                             const float* __restrict__ w1,
                                             float* __restrict__ Pab) {
    int idx = blockIdx.x * 256 + threadIdx.x;
    int n = idx >> 2, q = idx & 3;
    if (n >= NN) return;
    float m[MDIM];
    const float4* mr = (const float4*)(motif + (size_t)n * MDIM);
#pragma unroll
    for (int i = 0; i < 4; i++) {
        float4 t = mr[i];
        m[4 * i] = t.x; m[4 * i + 1] = t.y; m[4 * i + 2] = t.z; m[4 * i + 3] = t.w;
    }
    const float* wbase = (q < 2) ? (w1 + q * 32) : (w1 + MDIM * GHID + (q - 2) * 32);
    float h[32];
#pragma unroll
    for (int j = 0; j < 32; j++) h[j] = 0.0f;
#pragma unroll 1
    for (int k = 0; k < MDIM; k++) {
        float f = m[k];
        const float* w = wbase + k * GHID;
#pragma unroll
        for (int j = 0; j < 32; j++) h[j] = fmaf(f, w[j], h[j]);
    }
    float* op = Pab + (size_t)n * 128 + q * 32;
#pragma unroll
    for (int j4 = 0; j4 < 8; j4++)
        *(float4*)(op + 4 * j4) =
            make_float4(h[4 * j4], h[4 * j4 + 1], h[4 * j4 + 2], h[4 * j4 + 3]);
}

// ---------------- counting-sort scan (exclusive prefix of count) -----------
__global__ __launch_bounds__(256) void k_scan1(const int* __restrict__ count,
                                               int* __restrict__ rs,
                                               int* __restrict__ bsum) {
    __shared__ int sd[256];
    int tid = threadIdx.x;
    int base = blockIdx.x * 2048 + tid * 8;
    int loc[8]; int s = 0;
#pragma unroll
    for (int i = 0; i < 8; i++) {
        int idx = base + i;
        int v = (idx < NN) ? count[idx] : 0;
        loc[i] = s; s += v;
    }
    sd[tid] = s; __syncthreads();
    for (int off = 1; off < 256; off <<= 1) {
        int t = (tid >= off) ? sd[tid - off] : 0;
        __syncthreads();
        sd[tid] += t;
        __syncthreads();
    }
    int texcl = sd[tid] - s;
    if (tid == 255) bsum[blockIdx.x] = sd[255];
#pragma unroll
    for (int i = 0; i < 8; i++) {
        int idx = base + i;
        if (idx < NN) rs[idx] = texcl + loc[i];
    }
}

__global__ __launch_bounds__(64) void k_scan2(const int* __restrict__ bsum,
                                              int* __restrict__ boffs) {
    int tid = threadIdx.x;
    int v = (tid < 49) ? bsum[tid] : 0;
    int x = v;
#pragma unroll
    for (int off = 1; off < 64; off <<= 1) {
        int t = __shfl_up(x, off, 64);
        if (tid >= off) x += t;
    }
    boffs[tid] = x - v;  // exclusive
}

__global__ __launch_bounds__(256) void k_scan3(int* __restrict__ rs,
                                               const int* __restrict__ boffs,
                                               int* __restrict__ cursor) {
    int i = blockIdx.x * 256 + threadIdx.x;
    if (i < NN) {
        int v = rs[i] + boffs[i >> 11];
        rs[i] = v;
        cursor[i] = v;
    }
}

// ---------------- fill CSR: (src, dst) pairs sorted by dst -----------------
__global__ __launch_bounds__(256) void k_fill(
    const int* __restrict__ src, const int* __restrict__ dst,
    int* __restrict__ cursor, int* __restrict__ src_s,
    int* __restrict__ dst_s) {
    int e = blockIdx.x * 256 + threadIdx.x;
    if (e >= NE) return;
    int d = dst[e];
    int pos = atomicAdd(&cursor[d], 1);
    src_s[pos] = src[e];
    dst_s[pos] = d;
}

// ---------------- edge gate MLP in dst-sorted order ------------------------
// d-side reads (Pb[d], motif[d]) are near-sequential runs -> cache hits;
// only Pa[s], motif[s] random. h = Pa[s]+Pb[d]+b1 + |mu-mv|@W1c + (mu*mv)@W1d
__global__ __launch_bounds__(256, 4) void k_gate(
    const float* __restrict__ motif, const int* __restrict__ src_s,
    const int* __restrict__ dst_s, const float* __restrict__ Pab,
    const float* __restrict__ w1, const float* __restrict__ b1,
    const float* __restrict__ w2, const float* __restrict__ b2,
    float* __restrict__ g_s) {
    int e = blockIdx.x * 256 + threadIdx.x;
    if (e >= NE) return;
    int s = src_s[e], d = dst_s[e];
    float mu[MDIM], mv[MDIM];
    const float4* ms = (const float4*)(motif + (size_t)s * MDIM);
    const float4* mdp = (const float4*)(motif + (size_t)d * MDIM);
#pragma unroll
    for (int q = 0; q < 4; q++) {
        float4 a = ms[q], b = mdp[q];
        mu[4 * q] = a.x; mu[4 * q + 1] = a.y; mu[4 * q + 2] = a.z; mu[4 * q + 3] = a.w;
        mv[4 * q] = b.x; mv[4 * q + 1] = b.y; mv[4 * q + 2] = b.z; mv[4 * q + 3] = b.w;
    }
    const float4* pas = (const float4*)(Pab + (size_t)s * 128);
    const float4* pbd = (const float4*)(Pab + (size_t)d * 128 + 64);
    const float* w1c = w1 + 2 * MDIM * GHID;
    const float* w1d = w1 + 3 * MDIM * GHID;
    float g = b2[0];
#pragma unroll 1
    for (int jh = 0; jh < 2; jh++) {
        float h[32];
#pragma unroll
        for (int j4 = 0; j4 < 8; j4++) {
            float4 a = pas[jh * 8 + j4];
            float4 b = pbd[jh * 8 + j4];
            const float4 bb = *(const float4*)(b1 + jh * 32 + 4 * j4);
            h[4 * j4] = a.x + b.x + bb.x;
            h[4 * j4 + 1] = a.y + b.y + bb.y;
            h[4 * j4 + 2] = a.z + b.z + bb.z;
            h[4 * j4 + 3] = a.w + b.w + bb.w;
        }
#pragma unroll 1
        for (int k = 0; k < MDIM; k++) {
            float f0 = mu[k], f1 = mv[k];
            float f2 = fabsf(f0 - f1), f3 = f0 * f1;
            const float* wc = w1c + k * GHID + jh * 32;
            const float* wd = w1d + k * GHID + jh * 32;
#pragma unroll
            for (int j = 0; j < 32; j++) {
                h[j] = fmaf(f2, wc[j], h[j]);
                h[j] = fmaf(f3, wd[j], h[j]);
            }
        }
        const float* w2p = w2 + jh * 32;
#pragma unroll
        for (int j = 0; j < 32; j++) g = fmaf(fmaxf(h[j], 0.0f), w2p[j], g);
    }
    g_s[e] = 1.0f / (1.0f + __expf(-g));
}

// ---------------- deg = 1 + row-sum of sorted gates -> dinv (wave/node) ----
__global__ __launch_bounds__(256) void k_deg(const int* __restrict__ rowstart,
                                             const int* __restrict__ count,
                                             const float* __restrict__ g_s,
                                             float* __restrict__ dinv) {
    int n = blockIdx.x * 4 + (threadIdx.x >> 6);
    int lane = threadIdx.x & 63;
    if (n >= NN) return;
    int a = rowstart[n], cnt = count[n];
    float sum = 0.0f;
    for (int c = lane; c < cnt; c += 64) sum += g_s[a + c];
#pragma unroll
    for (int m = 1; m < 64; m <<= 1) sum += __shfl_xor(sum, m, 64);
    if (lane == 0) dinv[n] = rsqrtf(1.0f + sum);
}

// ---------------- g_s[e] *= dinv[src]*dinv[dst] (in-place, coalesced) ------
__global__ __launch_bounds__(256) void k_wnorm(
    const int* __restrict__ src_s, const int* __restrict__ dst_s,
    const float* __restrict__ dinv, float* __restrict__ g_s) {
    int e = blockIdx.x * 256 + threadIdx.x;
    if (e >= NE) return;
    g_s[e] *= dinv[src_s[e]] * dinv[dst_s[e]];
}

// ---------------- xw = A @ W (128x128) -------------------------------------
__global__ __launch_bounds__(256) void k_conv_gemm(
    const float* __restrict__ A, const float* __restrict__ Bw,
    float* __restrict__ xw) {
    __shared__ float sB[IND * IND];  // 64 KB
    int tid = threadIdx.x;
    {
        const float4* B4 = (const float4*)Bw;
        float4* s4 = (float4*)sB;
#pragma unroll
        for (int i = 0; i < 16; i++) s4[tid + 256 * i] = B4[tid + 256 * i];
    }
    __syncthreads();
    int cg = tid >> 5, rs = tid & 31;
    int row0 = blockIdx.x * 128 + rs * 4;
    int col0 = cg * 16;
    float acc[4][16];
#pragma unroll
    for (int j = 0; j < 4; j++)
#pragma unroll
        for (int c = 0; c < 16; c++) acc[j][c] = 0.0f;
    for (int k = 0; k < IND; k += 4) {
        float4 a[4];
#pragma unroll
        for (int j = 0; j < 4; j++) {
            int r = row0 + j;
            a[j] = (r < NN) ? *(const float4*)(A + (size_t)r * IND + k)
                            : make_float4(0.f, 0.f, 0.f, 0.f);
        }
#pragma unroll
        for (int kk = 0; kk < 4; kk++) {
            float b[16];
            const float4* bb = (const float4*)(sB + (k + kk) * IND + col0);
#pragma unroll
            for (int q = 0; q < 4; q++) {
                float4 t = bb[q];
                b[4 * q] = t.x; b[4 * q + 1] = t.y; b[4 * q + 2] = t.z; b[4 * q + 3] = t.w;
            }
#pragma unroll
            for (int j = 0; j < 4; j++) {
                float av = (kk == 0) ? a[j].x : (kk == 1) ? a[j].y : (kk == 2) ? a[j].z : a[j].w;
#pragma unroll
                for (int c = 0; c < 16; c++) acc[j][c] = fmaf(av, b[c], acc[j][c]);
            }
        }
    }
#pragma unroll
    for (int j = 0; j < 4; j++) {
        int r = row0 + j;
        if (r >= NN) continue;
        float* xo = xw + (size_t)r * IND + col0;
#pragma unroll
        for (int q = 0; q < 4; q++)
            *(float4*)(xo + 4 * q) =
                make_float4(acc[j][4 * q], acc[j][4 * q + 1], acc[j][4 * q + 2],
                            acc[j][4 * q + 3]);
    }
}

// ---------------- fused gather + bias + LN + relu + residual ---------------
__global__ __launch_bounds__(256) void k_aggr(
    const int* __restrict__ rowstart, const int* __restrict__ count,
    const int* __restrict__ src_s, const float* __restrict__ w_s,
    const float* __restrict__ xw, const float* __restrict__ dinv,
    const float* __restrict__ xold, float* __restrict__ xnew,
    const float* __restrict__ cb, const float* __restrict__ lg,
    const float* __restrict__ lb) {
    int n = blockIdx.x * 4 + (threadIdx.x >> 6);
    int lane = threadIdx.x & 63;
    if (n >= NN) return;
    const float2* xw2 = (const float2*)xw;
    float dn = dinv[n];
    float2 acc = xw2[(size_t)n * 64 + lane];  // self-loop: dinv[n]^2 * xw[n]
    acc.x *= dn * dn; acc.y *= dn * dn;
    int start = rowstart[n], cnt = count[n];
    for (int c = 0; c < cnt; c += 64) {
        int rem = cnt - c;
        int sv = 0; float wv = 0.0f;
        if (lane < rem) {
            sv = src_s[start + c + lane];
            wv = w_s[start + c + lane];
        }
        int m = rem < 64 ? rem : 64;
        int j = 0;
        for (; j + 4 <= m; j += 4) {  // 4 independent loads in flight
            int s0 = __shfl(sv, j, 64), s1 = __shfl(sv, j + 1, 64);
            int s2 = __shfl(sv, j + 2, 64), s3 = __shfl(sv, j + 3, 64);
            float w0 = __shfl(wv, j, 64), w1 = __shfl(wv, j + 1, 64);
            float w2 = __shfl(wv, j + 2, 64), w3 = __shfl(wv, j + 3, 64);
            float2 v0 = xw2[(size_t)s0 * 64 + lane];
            float2 v1 = xw2[(size_t)s1 * 64 + lane];
            float2 v2 = xw2[(size_t)s2 * 64 + lane];
            float2 v3 = xw2[(size_t)s3 * 64 + lane];
            acc.x = fmaf(w0, v0.x, acc.x); acc.y = fmaf(w0, v0.y, acc.y);
            acc.x = fmaf(w1, v1.x, acc.x); acc.y = fmaf(w1, v1.y, acc.y);
            acc.x = fmaf(w2, v2.x, acc.x); acc.y = fmaf(w2, v2.y, acc.y);
            acc.x = fmaf(w3, v3.x, acc.x); acc.y = fmaf(w3, v3.y, acc.y);
        }
        for (; j < m; j++) {
            int s = __shfl(sv, j, 64);
            float w = __shfl(wv, j, 64);
            float2 v = xw2[(size_t)s * 64 + lane];
            acc.x = fmaf(w, v.x, acc.x); acc.y = fmaf(w, v.y, acc.y);
        }
    }
    float2 cbv = ((const float2*)cb)[lane];
    acc.x += cbv.x; acc.y += cbv.y;
    float s1 = acc.x + acc.y, s2 = acc.x * acc.x + acc.y * acc.y;
#pragma unroll
    for (int mm = 1; mm < 64; mm <<= 1) {
        s1 += __shfl_xor(s1, mm, 64);
        s2 += __shfl_xor(s2, mm, 64);
    }
    float mean = s1 * (1.0f / 128.0f);
    float var = s2 * (1.0f / 128.0f) - mean * mean;
    float rstd = rsqrtf(var + 1e-5f);
    float2 lgv = ((const float2*)lg)[lane];
    float2 lbv = ((const float2*)lb)[lane];
    float y0 = fmaxf((acc.x - mean) * rstd * lgv.x + lbv.x, 0.0f);
    float y1 = fmaxf((acc.y - mean) * rstd * lgv.y + lbv.y, 0.0f);
    float2 xo = ((const float2*)xold)[(size_t)n * 64 + lane];
    ((float2*)xnew)[(size_t)n * 64 + lane] =
        make_float2(xo.x + y0, xo.y + y1);
}

// ---------------- head: out = A @ head_w + head_b --------------------------
__global__ __launch_bounds__(256) void k_head(
    const float* __restrict__ A, const float* __restrict__ Bw,
    const float* __restrict__ bias, float* __restrict__ out) {
    __shared__ float sB[IND * OUTD];  // 32 KB
    int tid = threadIdx.x;
    {
        const float4* B4 = (const float4*)Bw;
        float4* s4 = (float4*)sB;
#pragma unroll
        for (int i = 0; i < 8; i++) s4[tid + 256 * i] = B4[tid + 256 * i];
    }
    __syncthreads();
    int cg = tid >> 6, rs = tid & 63;
    int row0 = blockIdx.x * 128 + rs * 2;
    int col0 = cg * 16;
    float acc[2][16];
#pragma unroll
    for (int j = 0; j < 2; j++)
#pragma unroll
        for (int c = 0; c < 16; c++) acc[j][c] = 0.0f;
    for (int k = 0; k < IND; k += 4) {
        float4 a[2];
#pragma unroll
        for (int j = 0; j < 2; j++) {
            int r = row0 + j;
            a[j] = (r < NN) ? *(const float4*)(A + (size_t)r * IND + k)
                            : make_float4(0.f, 0.f, 0.f, 0.f);
        }
#pragma unroll
        for (int kk = 0; kk < 4; kk++) {
            float b[16];
            const float4* bb = (const float4*)(sB + (k + kk) * OUTD + col0);
#pragma unroll
            for (int q = 0; q < 4; q++) {
                float4 t = bb[q];
                b[4 * q] = t.x; b[4 * q + 1] = t.y; b[4 * q + 2] = t.z; b[4 * q + 3] = t.w;
            }
#pragma unroll
            for (int j = 0; j < 2; j++) {
                float av = (kk == 0) ? a[j].x : (kk == 1) ? a[j].y : (kk == 2) ? a[j].z : a[j].w;
#pragma unroll
                for (int c = 0; c < 16; c++) acc[j][c] = fmaf(av, b[c], acc[j][c]);
            }
        }
    }
#pragma unroll
    for (int j = 0; j < 2; j++) {
        int r = row0 + j;
        if (r >= NN) continue;
        float* op = out + (size_t)r * OUTD + col0;
#pragma unroll
        for (int q = 0; q < 4; q++) {
            float4 bs = *(const float4*)(bias + col0 + 4 * q);
            *(float4*)(op + 4 * q) =
                make_float4(acc[j][4 * q] + bs.x, acc[j][4 * q + 1] + bs.y,
                            acc[j][4 * q + 2] + bs.z, acc[j][4 * q + 3] + bs.w);
        }
    }
}

extern "C" void kernel_launch(void* const* d_in, const int* in_sizes, int n_in,
                              void* d_out, int out_size, void* d_ws,
                              size_t ws_size, hipStream_t stream) {
    const float* x = (const float*)d_in[0];
    const float* motif = (const float*)d_in[1];
    const void* ei = d_in[2];
    const float* gw1 = (const float*)d_in[3];
    const float* gb1 = (const float*)d_in[4];
    const float* gw2 = (const float*)d_in[5];
    const float* gb2 = (const float*)d_in[6];
    const float* cw = (const float*)d_in[7];   // [2,128,128]
    const float* cb = (const float*)d_in[8];   // [2,128]
    const float* lg = (const float*)d_in[9];
    const float* lb = (const float*)d_in[10];
    const float* hw = (const float*)d_in[11];  // [128,64]
    const float* hb = (const float*)d_in[12];
    float* out = (float*)d_out;

    float* ws = (float*)d_ws;
    size_t o = 0;
    float* dinv = ws + o; o += NN;
    int* idx32 = (int*)(ws + o); o += 2 * (size_t)NE;
    int* flag = (int*)(ws + o); o += 64;
    int* count = (int*)(ws + o); o += NN;
    int* rowstart = (int*)(ws + o); o += NN;
    int* cursor = (int*)(ws + o); o += NN;
    int* bsum = (int*)(ws + o); o += 64;
    int* boffs = (int*)(ws + o); o += 64;
    int* src_s = (int*)(ws + o); o += NE;
    int* dst_s = (int*)(ws + o); o += NE;
    float* g_s = ws + o; o += NE;
    float* xw = ws + o; o += (size_t)NN * IND;  // aliased with Pab (disjoint in time)
    float* xc = ws + o; o += (size_t)NN * IND;

    float* Pab = xw;  // alias: Pab dead before first k_conv_gemm writes xw

    const int* src = idx32;
    const int* dst = idx32 + NE;

    k_detect<<<1, 64, 0, stream>>>(ei, flag);
    k_convert<<<(2 * NE + 255) / 256, 256, 0, stream>>>(ei, flag, idx32);
    k_init<<<(NN + 255) / 256, 256, 0, stream>>>(count);
    k_hist<<<NE / 256, 256, 0, stream>>>(dst, count);
    k_pre<<<(4 * NN + 255) / 256, 256, 0, stream>>>(motif, gw1, Pab);

    // counting sort by dst -> CSR (shared by both layers)
    k_scan1<<<(NN + 2047) / 2048, 256, 0, stream>>>(count, rowstart, bsum);
    k_scan2<<<1, 64, 0, stream>>>(bsum, boffs);
    k_scan3<<<(NN + 255) / 256, 256, 0, stream>>>(rowstart, boffs, cursor);
    k_fill<<<NE / 256, 256, 0, stream>>>(src, dst, cursor, src_s, dst_s);

    // gate in dst-sorted order (d-side reads sequential), then deg, then norm
    k_gate<<<NE / 256, 256, 0, stream>>>(motif, src_s, dst_s, Pab, gw1, gb1,
                                         gw2, gb2, g_s);
    k_deg<<<(NN + 3) / 4, 256, 0, stream>>>(rowstart, count, g_s, dinv);
    k_wnorm<<<NE / 256, 256, 0, stream>>>(src_s, dst_s, dinv, g_s);

    // layer 0
    k_conv_gemm<<<(NN + 127) / 128, 256, 0, stream>>>(x, cw, xw);
    k_aggr<<<(NN + 3) / 4, 256, 0, stream>>>(rowstart, count, src_s, g_s, xw,
                                             dinv, x, xc, cb, lg, lb);
    // layer 1
    k_conv_gemm<<<(NN + 127) / 128, 256, 0, stream>>>(xc, cw + IND * IND, xw);
    k_aggr<<<(NN + 3) / 4, 256, 0, stream>>>(rowstart, count, src_s, g_s, xw,
                                             dinv, xc, xc, cb + IND, lg + IND,
                                             lb + IND);

    k_head<<<(NN + 127) / 128, 256, 0, stream>>>(xc, hw, hb, out);
}

// Round 6
// 902.645 us; speedup vs baseline: 1.2443x; 1.1605x over previous
//
#include <hip/hip_runtime.h>
#include <cstdint>
#include <cstddef>

#define NN 100000
#define NE 1600000
#define IND 128
#define OUTD 64
#define MDIM 16
#define GHID 64

// ---- bf16 helpers (RNE pack, exact unpack) --------------------------------
__device__ inline unsigned f2bf_pack(float a, float b) {
    unsigned ua = __float_as_uint(a);
    unsigned ub = __float_as_uint(b);
    unsigned ra = (ua + 0x7fffu + ((ua >> 16) & 1u)) >> 16;
    unsigned rb = (ub + 0x7fffu + ((ub >> 16) & 1u)) >> 16;
    return ra | (rb << 16);
}
__device__ inline float2 bf2x(unsigned u) {
    return make_float2(__uint_as_float(u << 16),
                       __uint_as_float(u & 0xffff0000u));
}

// ---------------- edge-index dtype detection (int32 vs int64) --------------
__global__ __launch_bounds__(64) void k_detect(const void* ei, int* flag) {
    const unsigned long long* p = (const unsigned long long*)ei;
    int i = threadIdx.x;
    unsigned long long v = p[(size_t)i * (NE / 64)];
    bool hi0 = (v >> 32) == 0ull;
    unsigned long long b = __ballot(hi0);
    if (i == 0) *flag = (b == ~0ull) ? 1 : 0;  // all high dwords zero -> int64
}

__global__ __launch_bounds__(256) void k_init(int* count) {
    int n = blockIdx.x * 256 + threadIdx.x;
    if (n < NN) count[n] = 0;
}

// ---------------- dst histogram straight from raw ei -----------------------
__global__ __launch_bounds__(256) void k_hist(const void* __restrict__ ei,
                                              const int* __restrict__ flag,
                                              int* __restrict__ count) {
    int e = blockIdx.x * 256 + threadIdx.x;
    if (e >= NE) return;
    int d = (*flag) ? (int)((const long long*)ei)[NE + e]
                    : ((const int*)ei)[NE + e];
    atomicAdd(&count[d], 1);
}

// ---------------- Pa/Pb precompute (bf16): row = [Pa(64) | Pb(64)] ---------
__global__ __launch_bounds__(256) void k_pre(const float* __restrict__ motif,
                                             const float* __restrict__ w1,
                                             unsigned* __restrict__ Pab) {
    int idx = blockIdx.x * 256 + threadIdx.x;
    int n = idx >> 2, q = idx & 3;
    if (n >= NN) return;
    float m[MDIM];
    const float4* mr = (const float4*)(motif + (size_t)n * MDIM);
#pragma unroll
    for (int i = 0; i < 4; i++) {
        float4 t = mr[i];
        m[4 * i] = t.x; m[4 * i + 1] = t.y; m[4 * i + 2] = t.z; m[4 * i + 3] = t.w;
    }
    const float* wbase = (q < 2) ? (w1 + q * 32) : (w1 + MDIM * GHID + (q - 2) * 32);
    float h[32];
#pragma unroll
    for (int j = 0; j < 32; j++) h[j] = 0.0f;
#pragma unroll 1
    for (int k = 0; k < MDIM; k++) {
        float f = m[k];
        const float* w = wbase + k * GHID;
#pragma unroll
        for (int j = 0; j < 32; j++) h[j] = fmaf(f, w[j], h[j]);
    }
    unsigned* op = Pab + (size_t)n * 64 + q * 16;  // uint = 2 bf16 channels
#pragma unroll
    for (int jj = 0; jj < 16; jj++) op[jj] = f2bf_pack(h[2 * jj], h[2 * jj + 1]);
}

// ---------------- counting-sort scan (exclusive prefix of count) -----------
__global__ __launch_bounds__(256) void k_scan1(const int* __restrict__ count,
                                               int* __restrict__ rs,
                                               int* __restrict__ bsum) {
    __shared__ int sd[256];
    int tid = threadIdx.x;
    int base = blockIdx.x * 2048 + tid * 8;
    int loc[8]; int s = 0;
#pragma unroll
    for (int i = 0; i < 8; i++) {
        int idx = base + i;
        int v = (idx < NN) ? count[idx] : 0;
        loc[i] = s; s += v;
    }
    sd[tid] = s; __syncthreads();
    for (int off = 1; off < 256; off <<= 1) {
        int t = (tid >= off) ? sd[tid - off] : 0;
        __syncthreads();
        sd[tid] += t;
        __syncthreads();
    }
    int texcl = sd[tid] - s;
    if (tid == 255) bsum[blockIdx.x] = sd[255];
#pragma unroll
    for (int i = 0; i < 8; i++) {
        int idx = base + i;
        if (idx < NN) rs[idx] = texcl + loc[i];
    }
}

__global__ __launch_bounds__(64) void k_scan2(const int* __restrict__ bsum,
                                              int* __restrict__ boffs) {
    int tid = threadIdx.x;
    int v = (tid < 49) ? bsum[tid] : 0;
    int x = v;
#pragma unroll
    for (int off = 1; off < 64; off <<= 1) {
        int t = __shfl_up(x, off, 64);
        if (tid >= off) x += t;
    }
    boffs[tid] = x - v;  // exclusive
}

__global__ __launch_bounds__(256) void k_scan3(int* __restrict__ rs,
                                               const int* __restrict__ boffs,
                                               int* __restrict__ cursor) {
    int i = blockIdx.x * 256 + threadIdx.x;
    if (i < NN) {
        int v = rs[i] + boffs[i >> 11];
        rs[i] = v;
        cursor[i] = v;
    }
}

// ---------------- fill CSR straight from raw ei: one int2 store per edge ---
__global__ __launch_bounds__(256) void k_fill(const void* __restrict__ ei,
                                              const int* __restrict__ flag,
                                              int* __restrict__ cursor,
                                              int2* __restrict__ es) {
    int e = blockIdx.x * 256 + threadIdx.x;
    if (e >= NE) return;
    int s, d;
    if (*flag) {
        s = (int)((const long long*)ei)[e];
        d = (int)((const long long*)ei)[NE + e];
    } else {
        s = ((const int*)ei)[e];
        d = ((const int*)ei)[NE + e];
    }
    int pos = atomicAdd(&cursor[d], 1);
    es[pos] = make_int2(s, d);
}

// ---------------- edge gate MLP in dst-sorted order ------------------------
// h = Pa[s] + Pb[d] + b1 + |mu-mv|@W1c + (mu*mv)@W1d   (Pa/Pb in bf16)
__global__ __launch_bounds__(256, 4) void k_gate(
    const float* __restrict__ motif, const int2* __restrict__ es,
    const unsigned* __restrict__ Pab, const float* __restrict__ w1,
    const float* __restrict__ b1, const float* __restrict__ w2,
    const float* __restrict__ b2, float* __restrict__ g_s) {
    int e = blockIdx.x * 256 + threadIdx.x;
    if (e >= NE) return;
    int2 sd = es[e];
    int s = sd.x, d = sd.y;
    float mu[MDIM], mv[MDIM];
    const float4* ms = (const float4*)(motif + (size_t)s * MDIM);
    const float4* mdp = (const float4*)(motif + (size_t)d * MDIM);
#pragma unroll
    for (int q = 0; q < 4; q++) {
        float4 a = ms[q], b = mdp[q];
        mu[4 * q] = a.x; mu[4 * q + 1] = a.y; mu[4 * q + 2] = a.z; mu[4 * q + 3] = a.w;
        mv[4 * q] = b.x; mv[4 * q + 1] = b.y; mv[4 * q + 2] = b.z; mv[4 * q + 3] = b.w;
    }
    const unsigned* pas = Pab + (size_t)s * 64;        // Pa: uints 0..31
    const unsigned* pbd = Pab + (size_t)d * 64 + 32;   // Pb: uints 32..63
    const float* w1c = w1 + 2 * MDIM * GHID;
    const float* w1d = w1 + 3 * MDIM * GHID;
    float g = b2[0];
#pragma unroll 1
    for (int jh = 0; jh < 2; jh++) {
        float h[32];
#pragma unroll
        for (int jj = 0; jj < 16; jj++) {
            float2 a = bf2x(pas[jh * 16 + jj]);
            float2 b = bf2x(pbd[jh * 16 + jj]);
            h[2 * jj] = a.x + b.x + b1[jh * 32 + 2 * jj];
            h[2 * jj + 1] = a.y + b.y + b1[jh * 32 + 2 * jj + 1];
        }
#pragma unroll 1
        for (int k = 0; k < MDIM; k++) {
            float f0 = mu[k], f1 = mv[k];
            float f2 = fabsf(f0 - f1), f3 = f0 * f1;
            const float* wc = w1c + k * GHID + jh * 32;
            const float* wd = w1d + k * GHID + jh * 32;
#pragma unroll
            for (int j = 0; j < 32; j++) {
                h[j] = fmaf(f2, wc[j], h[j]);
                h[j] = fmaf(f3, wd[j], h[j]);
            }
        }
        const float* w2p = w2 + jh * 32;
#pragma unroll
        for (int j = 0; j < 32; j++) g = fmaf(fmaxf(h[j], 0.0f), w2p[j], g);
    }
    g_s[e] = 1.0f / (1.0f + __expf(-g));
}

// ---------------- deg = 1 + row-sum of sorted gates -> dinv (wave/node) ----
__global__ __launch_bounds__(256) void k_deg(const int* __restrict__ rowstart,
                                             const int* __restrict__ count,
                                             const float* __restrict__ g_s,
                                             float* __restrict__ dinv) {
    int n = blockIdx.x * 4 + (threadIdx.x >> 6);
    int lane = threadIdx.x & 63;
    if (n >= NN) return;
    int a = rowstart[n], cnt = count[n];
    float sum = 0.0f;
    for (int c = lane; c < cnt; c += 64) sum += g_s[a + c];
#pragma unroll
    for (int m = 1; m < 64; m <<= 1) sum += __shfl_xor(sum, m, 64);
    if (lane == 0) dinv[n] = rsqrtf(1.0f + sum);
}

// ---------------- g_s[e] *= dinv[src]*dinv[dst] (in-place, coalesced) ------
__global__ __launch_bounds__(256) void k_wnorm(const int2* __restrict__ es,
                                               const float* __restrict__ dinv,
                                               float* __restrict__ g_s) {
    int e = blockIdx.x * 256 + threadIdx.x;
    if (e >= NE) return;
    int2 sd = es[e];
    g_s[e] *= dinv[sd.x] * dinv[sd.y];
}

// ---------------- xw = A @ W (128x128), output bf16-packed -----------------
__global__ __launch_bounds__(256) void k_conv_gemm(
    const float* __restrict__ A, const float* __restrict__ Bw,
    unsigned* __restrict__ xwb) {
    __shared__ float sB[IND * IND];  // 64 KB
    int tid = threadIdx.x;
    {
        const float4* B4 = (const float4*)Bw;
        float4* s4 = (float4*)sB;
#pragma unroll
        for (int i = 0; i < 16; i++) s4[tid + 256 * i] = B4[tid + 256 * i];
    }
    __syncthreads();
    int cg = tid >> 5, rs = tid & 31;
    int row0 = blockIdx.x * 128 + rs * 4;
    int col0 = cg * 16;
    float acc[4][16];
#pragma unroll
    for (int j = 0; j < 4; j++)
#pragma unroll
        for (int c = 0; c < 16; c++) acc[j][c] = 0.0f;
    for (int k = 0; k < IND; k += 4) {
        float4 a[4];
#pragma unroll
        for (int j = 0; j < 4; j++) {
            int r = row0 + j;
            a[j] = (r < NN) ? *(const float4*)(A + (size_t)r * IND + k)
                            : make_float4(0.f, 0.f, 0.f, 0.f);
        }
#pragma unroll
        for (int kk = 0; kk < 4; kk++) {
            float b[16];
            const float4* bb = (const float4*)(sB + (k + kk) * IND + col0);
#pragma unroll
            for (int q = 0; q < 4; q++) {
                float4 t = bb[q];
                b[4 * q] = t.x; b[4 * q + 1] = t.y; b[4 * q + 2] = t.z; b[4 * q + 3] = t.w;
            }
#pragma unroll
            for (int j = 0; j < 4; j++) {
                float av = (kk == 0) ? a[j].x : (kk == 1) ? a[j].y : (kk == 2) ? a[j].z : a[j].w;
#pragma unroll
                for (int c = 0; c < 16; c++) acc[j][c] = fmaf(av, b[c], acc[j][c]);
            }
        }
    }
#pragma unroll
    for (int j = 0; j < 4; j++) {
        int r = row0 + j;
        if (r >= NN) continue;
        unsigned* xo = xwb + (size_t)r * 64 + col0 / 2;
#pragma unroll
        for (int q = 0; q < 8; q++)
            xo[q] = f2bf_pack(acc[j][2 * q], acc[j][2 * q + 1]);
    }
}

// ---------------- fused gather(bf16) + bias + LN + relu + residual ---------
__global__ __launch_bounds__(256) void k_aggr(
    const int* __restrict__ rowstart, const int* __restrict__ count,
    const int2* __restrict__ es, const float* __restrict__ w_s,
    const unsigned* __restrict__ xwb, const float* __restrict__ dinv,
    const float* __restrict__ xold, float* __restrict__ xnew,
    const float* __restrict__ cb, const float* __restrict__ lg,
    const float* __restrict__ lb) {
    int n = blockIdx.x * 4 + (threadIdx.x >> 6);
    int lane = threadIdx.x & 63;
    if (n >= NN) return;
    float dn = dinv[n];
    float2 acc = bf2x(xwb[(size_t)n * 64 + lane]);  // self-loop
    acc.x *= dn * dn; acc.y *= dn * dn;
    int start = rowstart[n], cnt = count[n];
    for (int c = 0; c < cnt; c += 64) {
        int rem = cnt - c;
        int sv = 0; float wv = 0.0f;
        if (lane < rem) {
            sv = es[start + c + lane].x;
            wv = w_s[start + c + lane];
        }
        int m = rem < 64 ? rem : 64;
        int j = 0;
        for (; j + 4 <= m; j += 4) {  // 4 independent loads in flight
            int s0 = __shfl(sv, j, 64), s1 = __shfl(sv, j + 1, 64);
            int s2 = __shfl(sv, j + 2, 64), s3 = __shfl(sv, j + 3, 64);
            float w0 = __shfl(wv, j, 64), w1 = __shfl(wv, j + 1, 64);
            float w2 = __shfl(wv, j + 2, 64), w3 = __shfl(wv, j + 3, 64);
            unsigned u0 = xwb[(size_t)s0 * 64 + lane];
            unsigned u1 = xwb[(size_t)s1 * 64 + lane];
            unsigned u2 = xwb[(size_t)s2 * 64 + lane];
            unsigned u3 = xwb[(size_t)s3 * 64 + lane];
            float2 v0 = bf2x(u0), v1 = bf2x(u1), v2 = bf2x(u2), v3 = bf2x(u3);
            acc.x = fmaf(w0, v0.x, acc.x); acc.y = fmaf(w0, v0.y, acc.y);
            acc.x = fmaf(w1, v1.x, acc.x); acc.y = fmaf(w1, v1.y, acc.y);
            acc.x = fmaf(w2, v2.x, acc.x); acc.y = fmaf(w2, v2.y, acc.y);
            acc.x = fmaf(w3, v3.x, acc.x); acc.y = fmaf(w3, v3.y, acc.y);
        }
        for (; j < m; j++) {
            int s = __shfl(sv, j, 64);
            float w = __shfl(wv, j, 64);
            float2 v = bf2x(xwb[(size_t)s * 64 + lane]);
            acc.x = fmaf(w, v.x, acc.x); acc.y = fmaf(w, v.y, acc.y);
        }
    }
    float2 cbv = ((const float2*)cb)[lane];
    acc.x += cbv.x; acc.y += cbv.y;
    float s1 = acc.x + acc.y, s2 = acc.x * acc.x + acc.y * acc.y;
#pragma unroll
    for (int mm = 1; mm < 64; mm <<= 1) {
        s1 += __shfl_xor(s1, mm, 64);
        s2 += __shfl_xor(s2, mm, 64);
    }
    float mean = s1 * (1.0f / 128.0f);
    float var = s2 * (1.0f / 128.0f) - mean * mean;
    float rstd = rsqrtf(var + 1e-5f);
    float2 lgv = ((const float2*)lg)[lane];
    float2 lbv = ((const float2*)lb)[lane];
    float y0 = fmaxf((acc.x - mean) * rstd * lgv.x + lbv.x, 0.0f);
    float y1 = fmaxf((acc.y - mean) * rstd * lgv.y + lbv.y, 0.0f);
    float2 xo = ((const float2*)xold)[(size_t)n * 64 + lane];
    ((float2*)xnew)[(size_t)n * 64 + lane] =
        make_float2(xo.x + y0, xo.y + y1);
}

// ---------------- head: out = A @ head_w + head_b --------------------------
__global__ __launch_bounds__(256) void k_head(
    const float* __restrict__ A, const float* __restrict__ Bw,
    const float* __restrict__ bias, float* __restrict__ out) {
    __shared__ float sB[IND * OUTD];  // 32 KB
    int tid = threadIdx.x;
    {
        const float4* B4 = (const float4*)Bw;
        float4* s4 = (float4*)sB;
#pragma unroll
        for (int i = 0; i < 8; i++) s4[tid + 256 * i] = B4[tid + 256 * i];
    }
    __syncthreads();
    int cg = tid >> 6, rs = tid & 63;
    int row0 = blockIdx.x * 128 + rs * 2;
    int col0 = cg * 16;
    float acc[2][16];
#pragma unroll
    for (int j = 0; j < 2; j++)
#pragma unroll
        for (int c = 0; c < 16; c++) acc[j][c] = 0.0f;
    for (int k = 0; k < IND; k += 4) {
        float4 a[2];
#pragma unroll
        for (int j = 0; j < 2; j++) {
            int r = row0 + j;
            a[j] = (r < NN) ? *(const float4*)(A + (size_t)r * IND + k)
                            : make_float4(0.f, 0.f, 0.f, 0.f);
        }
#pragma unroll
        for (int kk = 0; kk < 4; kk++) {
            float b[16];
            const float4* bb = (const float4*)(sB + (k + kk) * OUTD + col0);
#pragma unroll
            for (int q = 0; q < 4; q++) {
                float4 t = bb[q];
                b[4 * q] = t.x; b[4 * q + 1] = t.y; b[4 * q + 2] = t.z; b[4 * q + 3] = t.w;
            }
#pragma unroll
            for (int j = 0; j < 2; j++) {
                float av = (kk == 0) ? a[j].x : (kk == 1) ? a[j].y : (kk == 2) ? a[j].z : a[j].w;
#pragma unroll
                for (int c = 0; c < 16; c++) acc[j][c] = fmaf(av, b[c], acc[j][c]);
            }
        }
    }
#pragma unroll
    for (int j = 0; j < 2; j++) {
        int r = row0 + j;
        if (r >= NN) continue;
        float* op = out + (size_t)r * OUTD + col0;
#pragma unroll
        for (int q = 0; q < 4; q++) {
            float4 bs = *(const float4*)(bias + col0 + 4 * q);
            *(float4*)(op + 4 * q) =
                make_float4(acc[j][4 * q] + bs.x, acc[j][4 * q + 1] + bs.y,
                            acc[j][4 * q + 2] + bs.z, acc[j][4 * q + 3] + bs.w);
        }
    }
}

extern "C" void kernel_launch(void* const* d_in, const int* in_sizes, int n_in,
                              void* d_out, int out_size, void* d_ws,
                              size_t ws_size, hipStream_t stream) {
    const float* x = (const float*)d_in[0];
    const float* motif = (const float*)d_in[1];
    const void* ei = d_in[2];
    const float* gw1 = (const float*)d_in[3];
    const float* gb1 = (const float*)d_in[4];
    const float* gw2 = (const float*)d_in[5];
    const float* gb2 = (const float*)d_in[6];
    const float* cw = (const float*)d_in[7];   // [2,128,128]
    const float* cb = (const float*)d_in[8];   // [2,128]
    const float* lg = (const float*)d_in[9];
    const float* lb = (const float*)d_in[10];
    const float* hw = (const float*)d_in[11];  // [128,64]
    const float* hb = (const float*)d_in[12];
    float* out = (float*)d_out;

    float* ws = (float*)d_ws;
    size_t o = 0;
    float* dinv = ws + o; o += NN;
    int* flag = (int*)(ws + o); o += 64;
    int* count = (int*)(ws + o); o += NN;
    int* rowstart = (int*)(ws + o); o += NN;
    int* cursor = (int*)(ws + o); o += NN;
    int* bsum = (int*)(ws + o); o += 64;
    int* boffs = (int*)(ws + o); o += 64;
    int2* es = (int2*)(ws + o); o += 2 * (size_t)NE;
    float* g_s = ws + o; o += NE;
    unsigned* xwb = (unsigned*)(ws + o); o += (size_t)NN * 64;  // bf16 xw, aliases Pab
    float* xc = ws + o; o += (size_t)NN * IND;

    unsigned* Pab = xwb;  // alias: Pab dead before first k_conv_gemm writes xwb

    k_detect<<<1, 64, 0, stream>>>(ei, flag);
    k_init<<<(NN + 255) / 256, 256, 0, stream>>>(count);
    k_hist<<<NE / 256, 256, 0, stream>>>(ei, flag, count);
    k_pre<<<(4 * NN + 255) / 256, 256, 0, stream>>>(motif, gw1, Pab);

    // counting sort by dst -> CSR (shared by both layers)
    k_scan1<<<(NN + 2047) / 2048, 256, 0, stream>>>(count, rowstart, bsum);
    k_scan2<<<1, 64, 0, stream>>>(bsum, boffs);
    k_scan3<<<(NN + 255) / 256, 256, 0, stream>>>(rowstart, boffs, cursor);
    k_fill<<<NE / 256, 256, 0, stream>>>(ei, flag, cursor, es);

    // gate in dst-sorted order, then deg, then normalize weights in place
    k_gate<<<NE / 256, 256, 0, stream>>>(motif, es, Pab, gw1, gb1, gw2, gb2,
                                         g_s);
    k_deg<<<(NN + 3) / 4, 256, 0, stream>>>(rowstart, count, g_s, dinv);
    k_wnorm<<<NE / 256, 256, 0, stream>>>(es, dinv, g_s);

    // layer 0
    k_conv_gemm<<<(NN + 127) / 128, 256, 0, stream>>>(x, cw, xwb);
    k_aggr<<<(NN + 3) / 4, 256, 0, stream>>>(rowstart, count, es, g_s, xwb,
                                             dinv, x, xc, cb, lg, lb);
    // layer 1
    k_conv_gemm<<<(NN + 127) / 128, 256, 0, stream>>>(xc, cw + IND * IND, xwb);
    k_aggr<<<(NN + 3) / 4, 256, 0, stream>>>(rowstart, count, es, g_s, xwb,
                                             dinv, xc, xc, cb + IND, lg + IND,
                                             lb + IND);

    k_head<<<(NN + 127) / 128, 256, 0, stream>>>(xc, hw, hb, out);
}

// Round 7
// 862.079 us; speedup vs baseline: 1.3028x; 1.0471x over previous
//
#include <hip/hip_runtime.h>
#include <cstdint>
#include <cstddef>

#define NN 100000
#define NE 1600000
#define IND 128
#define OUTD 64
#define MDIM 16
#define GHID 64
#define NPART 12500  // NN / 8 XCDs

// ---- bf16 helpers (RNE pack, exact unpack) --------------------------------
__device__ inline unsigned f2bf_pack(float a, float b) {
    unsigned ua = __float_as_uint(a);
    unsigned ub = __float_as_uint(b);
    unsigned ra = (ua + 0x7fffu + ((ua >> 16) & 1u)) >> 16;
    unsigned rb = (ub + 0x7fffu + ((ub >> 16) & 1u)) >> 16;
    return ra | (rb << 16);
}
__device__ inline float2 bf2x(unsigned u) {
    return make_float2(__uint_as_float(u << 16),
                       __uint_as_float(u & 0xffff0000u));
}

// ---------------- edge-index dtype detection (int32 vs int64) --------------
__global__ __launch_bounds__(64) void k_detect(const void* ei, int* flag) {
    const unsigned long long* p = (const unsigned long long*)ei;
    int i = threadIdx.x;
    unsigned long long v = p[(size_t)i * (NE / 64)];
    bool hi0 = (v >> 32) == 0ull;
    unsigned long long b = __ballot(hi0);
    if (i == 0) *flag = (b == ~0ull) ? 1 : 0;  // all high dwords zero -> int64
}

__global__ __launch_bounds__(256) void k_init(int* count) {
    int n = blockIdx.x * 256 + threadIdx.x;
    if (n < NN) count[n] = 0;
}

// ---------------- dst histogram straight from raw ei -----------------------
__global__ __launch_bounds__(256) void k_hist(const void* __restrict__ ei,
                                              const int* __restrict__ flag,
                                              int* __restrict__ count) {
    int e = blockIdx.x * 256 + threadIdx.x;
    if (e >= NE) return;
    int d = (*flag) ? (int)((const long long*)ei)[NE + e]
                    : ((const int*)ei)[NE + e];
    atomicAdd(&count[d], 1);
}

// ---------------- Pa/Pb precompute (bf16): row = [Pa(64) | Pb(64)] ---------
__global__ __launch_bounds__(256) void k_pre(const float* __restrict__ motif,
                                             const float* __restrict__ w1,
                                             unsigned* __restrict__ Pab) {
    int idx = blockIdx.x * 256 + threadIdx.x;
    int n = idx >> 2, q = idx & 3;
    if (n >= NN) return;
    float m[MDIM];
    const float4* mr = (const float4*)(motif + (size_t)n * MDIM);
#pragma unroll
    for (int i = 0; i < 4; i++) {
        float4 t = mr[i];
        m[4 * i] = t.x; m[4 * i + 1] = t.y; m[4 * i + 2] = t.z; m[4 * i + 3] = t.w;
    }
    const float* wbase = (q < 2) ? (w1 + q * 32) : (w1 + MDIM * GHID + (q - 2) * 32);
    float h[32];
#pragma unroll
    for (int j = 0; j < 32; j++) h[j] = 0.0f;
#pragma unroll 1
    for (int k = 0; k < MDIM; k++) {
        float f = m[k];
        const float* w = wbase + k * GHID;
#pragma unroll
        for (int j = 0; j < 32; j++) h[j] = fmaf(f, w[j], h[j]);
    }
    unsigned* op = Pab + (size_t)n * 64 + q * 16;  // uint = 2 bf16 channels
#pragma unroll
    for (int jj = 0; jj < 16; jj++) op[jj] = f2bf_pack(h[2 * jj], h[2 * jj + 1]);
}

// ---------------- counting-sort scan (exclusive prefix of count) -----------
__global__ __launch_bounds__(256) void k_scan1(const int* __restrict__ count,
                                               int* __restrict__ rs,
                                               int* __restrict__ bsum) {
    __shared__ int sd[256];
    int tid = threadIdx.x;
    int base = blockIdx.x * 2048 + tid * 8;
    int loc[8]; int s = 0;
#pragma unroll
    for (int i = 0; i < 8; i++) {
        int idx = base + i;
        int v = (idx < NN) ? count[idx] : 0;
        loc[i] = s; s += v;
    }
    sd[tid] = s; __syncthreads();
    for (int off = 1; off < 256; off <<= 1) {
        int t = (tid >= off) ? sd[tid - off] : 0;
        __syncthreads();
        sd[tid] += t;
        __syncthreads();
    }
    int texcl = sd[tid] - s;
    if (tid == 255) bsum[blockIdx.x] = sd[255];
#pragma unroll
    for (int i = 0; i < 8; i++) {
        int idx = base + i;
        if (idx < NN) rs[idx] = texcl + loc[i];
    }
}

__global__ __launch_bounds__(64) void k_scan2(const int* __restrict__ bsum,
                                              int* __restrict__ boffs) {
    int tid = threadIdx.x;
    int v = (tid < 49) ? bsum[tid] : 0;
    int x = v;
#pragma unroll
    for (int off = 1; off < 64; off <<= 1) {
        int t = __shfl_up(x, off, 64);
        if (tid >= off) x += t;
    }
    boffs[tid] = x - v;  // exclusive
}

__global__ __launch_bounds__(256) void k_scan3(int* __restrict__ rs,
                                               const int* __restrict__ boffs,
                                               int* __restrict__ cursor) {
    int i = blockIdx.x * 256 + threadIdx.x;
    if (i < NN) {
        int v = rs[i] + boffs[i >> 11];
        rs[i] = v;
        cursor[i] = v;
    }
}

// ---------------- fill CSR, XCD-partitioned by dst range -------------------
// partition p = blockIdx % 8 (XCD round-robin heuristic): all writes for
// node range [p*12500,(p+1)*12500) come from one XCD, so its L2 merges the
// 8B scatters into full lines (round-6: WRITE_SIZE 100 MB = 64 B/edge).
__global__ __launch_bounds__(256) void k_fill(const void* __restrict__ ei,
                                              const int* __restrict__ flag,
                                              int* __restrict__ cursor,
                                              int2* __restrict__ es) {
    int p = blockIdx.x & 7;
    int base = (blockIdx.x >> 3) * 2048;
    bool is64 = (*flag) != 0;
#pragma unroll 1
    for (int it = 0; it < 8; it++) {
        int e = base + it * 256 + threadIdx.x;
        if (e >= NE) break;
        int d = is64 ? (int)((const long long*)ei)[NE + e]
                     : ((const int*)ei)[NE + e];
        if ((unsigned)d / NPART != (unsigned)p) continue;
        int s = is64 ? (int)((const long long*)ei)[e] : ((const int*)ei)[e];
        int pos = atomicAdd(&cursor[d], 1);
        es[pos] = make_int2(s, d);
    }
}

// ---------------- edge gate MLP in dst-sorted order ------------------------
// h = Pa[s] + Pb[d] + b1 + |mu-mv|@W1c + (mu*mv)@W1d   (Pa/Pb in bf16)
__global__ __launch_bounds__(256, 4) void k_gate(
    const float* __restrict__ motif, const int2* __restrict__ es,
    const unsigned* __restrict__ Pab, const float* __restrict__ w1,
    const float* __restrict__ b1, const float* __restrict__ w2,
    const float* __restrict__ b2, float* __restrict__ g_s) {
    int e = blockIdx.x * 256 + threadIdx.x;
    if (e >= NE) return;
    int2 sd = es[e];
    int s = sd.x, d = sd.y;
    float mu[MDIM], mv[MDIM];
    const float4* ms = (const float4*)(motif + (size_t)s * MDIM);
    const float4* mdp = (const float4*)(motif + (size_t)d * MDIM);
#pragma unroll
    for (int q = 0; q < 4; q++) {
        float4 a = ms[q], b = mdp[q];
        mu[4 * q] = a.x; mu[4 * q + 1] = a.y; mu[4 * q + 2] = a.z; mu[4 * q + 3] = a.w;
        mv[4 * q] = b.x; mv[4 * q + 1] = b.y; mv[4 * q + 2] = b.z; mv[4 * q + 3] = b.w;
    }
    const unsigned* pas = Pab + (size_t)s * 64;        // Pa: uints 0..31
    const unsigned* pbd = Pab + (size_t)d * 64 + 32;   // Pb: uints 32..63
    const float* w1c = w1 + 2 * MDIM * GHID;
    const float* w1d = w1 + 3 * MDIM * GHID;
    float g = b2[0];
#pragma unroll 1
    for (int jh = 0; jh < 2; jh++) {
        float h[32];
#pragma unroll
        for (int jj = 0; jj < 16; jj++) {
            float2 a = bf2x(pas[jh * 16 + jj]);
            float2 b = bf2x(pbd[jh * 16 + jj]);
            h[2 * jj] = a.x + b.x + b1[jh * 32 + 2 * jj];
            h[2 * jj + 1] = a.y + b.y + b1[jh * 32 + 2 * jj + 1];
        }
#pragma unroll 1
        for (int k = 0; k < MDIM; k++) {
            float f0 = mu[k], f1 = mv[k];
            float f2 = fabsf(f0 - f1), f3 = f0 * f1;
            const float* wc = w1c + k * GHID + jh * 32;
            const float* wd = w1d + k * GHID + jh * 32;
#pragma unroll
            for (int j = 0; j < 32; j++) {
                h[j] = fmaf(f2, wc[j], h[j]);
                h[j] = fmaf(f3, wd[j], h[j]);
            }
        }
        const float* w2p = w2 + jh * 32;
#pragma unroll
        for (int j = 0; j < 32; j++) g = fmaf(fmaxf(h[j], 0.0f), w2p[j], g);
    }
    g_s[e] = 1.0f / (1.0f + __expf(-g));
}

// ---------------- deg = 1 + row-sum of sorted gates -> dinv (wave/node) ----
__global__ __launch_bounds__(256) void k_deg(const int* __restrict__ rowstart,
                                             const int* __restrict__ count,
                                             const float* __restrict__ g_s,
                                             float* __restrict__ dinv) {
    int n = blockIdx.x * 4 + (threadIdx.x >> 6);
    int lane = threadIdx.x & 63;
    if (n >= NN) return;
    int a = rowstart[n], cnt = count[n];
    float sum = 0.0f;
    for (int c = lane; c < cnt; c += 64) sum += g_s[a + c];
#pragma unroll
    for (int m = 1; m < 64; m <<= 1) sum += __shfl_xor(sum, m, 64);
    if (lane == 0) dinv[n] = rsqrtf(1.0f + sum);
}

// ---------------- g_s[e] *= dinv[src]*dinv[dst] (in-place, coalesced) ------
__global__ __launch_bounds__(256) void k_wnorm(const int2* __restrict__ es,
                                               const float* __restrict__ dinv,
                                               float* __restrict__ g_s) {
    int e = blockIdx.x * 256 + threadIdx.x;
    if (e >= NE) return;
    int2 sd = es[e];
    g_s[e] *= dinv[sd.x] * dinv[sd.y];
}

// ---------------- xw = A @ W (128x128), output bf16-packed -----------------
__global__ __launch_bounds__(256) void k_conv_gemm(
    const float* __restrict__ A, const float* __restrict__ Bw,
    unsigned* __restrict__ xwb) {
    __shared__ float sB[IND * IND];  // 64 KB
    int tid = threadIdx.x;
    {
        const float4* B4 = (const float4*)Bw;
        float4* s4 = (float4*)sB;
#pragma unroll
        for (int i = 0; i < 16; i++) s4[tid + 256 * i] = B4[tid + 256 * i];
    }
    __syncthreads();
    int cg = tid >> 5, rs = tid & 31;
    int row0 = blockIdx.x * 128 + rs * 4;
    int col0 = cg * 16;
    float acc[4][16];
#pragma unroll
    for (int j = 0; j < 4; j++)
#pragma unroll
        for (int c = 0; c < 16; c++) acc[j][c] = 0.0f;
    for (int k = 0; k < IND; k += 4) {
        float4 a[4];
#pragma unroll
        for (int j = 0; j < 4; j++) {
            int r = row0 + j;
            a[j] = (r < NN) ? *(const float4*)(A + (size_t)r * IND + k)
                            : make_float4(0.f, 0.f, 0.f, 0.f);
        }
#pragma unroll
        for (int kk = 0; kk < 4; kk++) {
            float b[16];
            const float4* bb = (const float4*)(sB + (k + kk) * IND + col0);
#pragma unroll
            for (int q = 0; q < 4; q++) {
                float4 t = bb[q];
                b[4 * q] = t.x; b[4 * q + 1] = t.y; b[4 * q + 2] = t.z; b[4 * q + 3] = t.w;
            }
#pragma unroll
            for (int j = 0; j < 4; j++) {
                float av = (kk == 0) ? a[j].x : (kk == 1) ? a[j].y : (kk == 2) ? a[j].z : a[j].w;
#pragma unroll
                for (int c = 0; c < 16; c++) acc[j][c] = fmaf(av, b[c], acc[j][c]);
            }
        }
    }
#pragma unroll
    for (int j = 0; j < 4; j++) {
        int r = row0 + j;
        if (r >= NN) continue;
        unsigned* xo = xwb + (size_t)r * 64 + col0 / 2;
#pragma unroll
        for (int q = 0; q < 8; q++)
            xo[q] = f2bf_pack(acc[j][2 * q], acc[j][2 * q + 1]);
    }
}

// ---------------- fused gather(bf16) + bias + LN + relu + residual ---------
__global__ __launch_bounds__(256) void k_aggr(
    const int* __restrict__ rowstart, const int* __restrict__ count,
    const int2* __restrict__ es, const float* __restrict__ w_s,
    const unsigned* __restrict__ xwb, const float* __restrict__ dinv,
    const float* __restrict__ xold, float* __restrict__ xnew,
    const float* __restrict__ cb, const float* __restrict__ lg,
    const float* __restrict__ lb) {
    int n = blockIdx.x * 4 + (threadIdx.x >> 6);
    int lane = threadIdx.x & 63;
    if (n >= NN) return;
    float dn = dinv[n];
    float2 acc = bf2x(xwb[(size_t)n * 64 + lane]);  // self-loop
    acc.x *= dn * dn; acc.y *= dn * dn;
    int start = rowstart[n], cnt = count[n];
    for (int c = 0; c < cnt; c += 64) {
        int rem = cnt - c;
        int sv = 0; float wv = 0.0f;
        if (lane < rem) {
            sv = es[start + c + lane].x;
            wv = w_s[start + c + lane];
        }
        int m = rem < 64 ? rem : 64;
        int j = 0;
        for (; j + 4 <= m; j += 4) {  // 4 independent loads in flight
            int s0 = __shfl(sv, j, 64), s1 = __shfl(sv, j + 1, 64);
            int s2 = __shfl(sv, j + 2, 64), s3 = __shfl(sv, j + 3, 64);
            float w0 = __shfl(wv, j, 64), w1 = __shfl(wv, j + 1, 64);
            float w2 = __shfl(wv, j + 2, 64), w3 = __shfl(wv, j + 3, 64);
            unsigned u0 = xwb[(size_t)s0 * 64 + lane];
            unsigned u1 = xwb[(size_t)s1 * 64 + lane];
            unsigned u2 = xwb[(size_t)s2 * 64 + lane];
            unsigned u3 = xwb[(size_t)s3 * 64 + lane];
            float2 v0 = bf2x(u0), v1 = bf2x(u1), v2 = bf2x(u2), v3 = bf2x(u3);
            acc.x = fmaf(w0, v0.x, acc.x); acc.y = fmaf(w0, v0.y, acc.y);
            acc.x = fmaf(w1, v1.x, acc.x); acc.y = fmaf(w1, v1.y, acc.y);
            acc.x = fmaf(w2, v2.x, acc.x); acc.y = fmaf(w2, v2.y, acc.y);
            acc.x = fmaf(w3, v3.x, acc.x); acc.y = fmaf(w3, v3.y, acc.y);
        }
        for (; j < m; j++) {
            int s = __shfl(sv, j, 64);
            float w = __shfl(wv, j, 64);
            float2 v = bf2x(xwb[(size_t)s * 64 + lane]);
            acc.x = fmaf(w, v.x, acc.x); acc.y = fmaf(w, v.y, acc.y);
        }
    }
    float2 cbv = ((const float2*)cb)[lane];
    acc.x += cbv.x; acc.y += cbv.y;
    float s1 = acc.x + acc.y, s2 = acc.x * acc.x + acc.y * acc.y;
#pragma unroll
    for (int mm = 1; mm < 64; mm <<= 1) {
        s1 += __shfl_xor(s1, mm, 64);
        s2 += __shfl_xor(s2, mm, 64);
    }
    float mean = s1 * (1.0f / 128.0f);
    float var = s2 * (1.0f / 128.0f) - mean * mean;
    float rstd = rsqrtf(var + 1e-5f);
    float2 lgv = ((const float2*)lg)[lane];
    float2 lbv = ((const float2*)lb)[lane];
    float y0 = fmaxf((acc.x - mean) * rstd * lgv.x + lbv.x, 0.0f);
    float y1 = fmaxf((acc.y - mean) * rstd * lgv.y + lbv.y, 0.0f);
    float2 xo = ((const float2*)xold)[(size_t)n * 64 + lane];
    ((float2*)xnew)[(size_t)n * 64 + lane] =
        make_float2(xo.x + y0, xo.y + y1);
}

// ---------------- head: out = A @ head_w + head_b --------------------------
__global__ __launch_bounds__(256) void k_head(
    const float* __restrict__ A, const float* __restrict__ Bw,
    const float* __restrict__ bias, float* __restrict__ out) {
    __shared__ float sB[IND * OUTD];  // 32 KB
    int tid = threadIdx.x;
    {
        const float4* B4 = (const float4*)Bw;
        float4* s4 = (float4*)sB;
#pragma unroll
        for (int i = 0; i < 8; i++) s4[tid + 256 * i] = B4[tid + 256 * i];
    }
    __syncthreads();
    int cg = tid >> 6, rs = tid & 63;
    int row0 = blockIdx.x * 128 + rs * 2;
    int col0 = cg * 16;
    float acc[2][16];
#pragma unroll
    for (int j = 0; j < 2; j++)
#pragma unroll
        for (int c = 0; c < 16; c++) acc[j][c] = 0.0f;
    for (int k = 0; k < IND; k += 4) {
        float4 a[2];
#pragma unroll
        for (int j = 0; j < 2; j++) {
            int r = row0 + j;
            a[j] = (r < NN) ? *(const float4*)(A + (size_t)r * IND + k)
                            : make_float4(0.f, 0.f, 0.f, 0.f);
        }
#pragma unroll
        for (int kk = 0; kk < 4; kk++) {
            float b[16];
            const float4* bb = (const float4*)(sB + (k + kk) * OUTD + col0);
#pragma unroll
            for (int q = 0; q < 4; q++) {
                float4 t = bb[q];
                b[4 * q] = t.x; b[4 * q + 1] = t.y; b[4 * q + 2] = t.z; b[4 * q + 3] = t.w;
            }
#pragma unroll
            for (int j = 0; j < 2; j++) {
                float av = (kk == 0) ? a[j].x : (kk == 1) ? a[j].y : (kk == 2) ? a[j].z : a[j].w;
#pragma unroll
                for (int c = 0; c < 16; c++) acc[j][c] = fmaf(av, b[c], acc[j][c]);
            }
        }
    }
#pragma unroll
    for (int j = 0; j < 2; j++) {
        int r = row0 + j;
        if (r >= NN) continue;
        float* op = out + (size_t)r * OUTD + col0;
#pragma unroll
        for (int q = 0; q < 4; q++) {
            float4 bs = *(const float4*)(bias + col0 + 4 * q);
            *(float4*)(op + 4 * q) =
                make_float4(acc[j][4 * q] + bs.x, acc[j][4 * q + 1] + bs.y,
                            acc[j][4 * q + 2] + bs.z, acc[j][4 * q + 3] + bs.w);
        }
    }
}

extern "C" void kernel_launch(void* const* d_in, const int* in_sizes, int n_in,
                              void* d_out, int out_size, void* d_ws,
                              size_t ws_size, hipStream_t stream) {
    const float* x = (const float*)d_in[0];
    const float* motif = (const float*)d_in[1];
    const void* ei = d_in[2];
    const float* gw1 = (const float*)d_in[3];
    const float* gb1 = (const float*)d_in[4];
    const float* gw2 = (const float*)d_in[5];
    const float* gb2 = (const float*)d_in[6];
    const float* cw = (const float*)d_in[7];   // [2,128,128]
    const float* cb = (const float*)d_in[8];   // [2,128]
    const float* lg = (const float*)d_in[9];
    const float* lb = (const float*)d_in[10];
    const float* hw = (const float*)d_in[11];  // [128,64]
    const float* hb = (const float*)d_in[12];
    float* out = (float*)d_out;

    float* ws = (float*)d_ws;
    size_t o = 0;
    float* dinv = ws + o; o += NN;
    int* flag = (int*)(ws + o); o += 64;
    int* count = (int*)(ws + o); o += NN;
    int* rowstart = (int*)(ws + o); o += NN;
    int* cursor = (int*)(ws + o); o += NN;
    int* bsum = (int*)(ws + o); o += 64;
    int* boffs = (int*)(ws + o); o += 64;
    int2* es = (int2*)(ws + o); o += 2 * (size_t)NE;
    float* g_s = ws + o; o += NE;
    unsigned* xwb = (unsigned*)(ws + o); o += (size_t)NN * 64;  // bf16 xw, aliases Pab
    float* xc = ws + o; o += (size_t)NN * IND;

    unsigned* Pab = xwb;  // alias: Pab dead before first k_conv_gemm writes xwb

    k_detect<<<1, 64, 0, stream>>>(ei, flag);
    k_init<<<(NN + 255) / 256, 256, 0, stream>>>(count);
    k_hist<<<NE / 256, 256, 0, stream>>>(ei, flag, count);
    k_pre<<<(4 * NN + 255) / 256, 256, 0, stream>>>(motif, gw1, Pab);

    // counting sort by dst -> CSR (shared by both layers)
    k_scan1<<<(NN + 2047) / 2048, 256, 0, stream>>>(count, rowstart, bsum);
    k_scan2<<<1, 64, 0, stream>>>(bsum, boffs);
    k_scan3<<<(NN + 255) / 256, 256, 0, stream>>>(rowstart, boffs, cursor);
    // XCD-partitioned fill: 8 partitions x ceil(NE/2048) chunks
    k_fill<<<8 * ((NE + 2047) / 2048), 256, 0, stream>>>(ei, flag, cursor, es);

    // gate in dst-sorted order, then deg, then normalize weights in place
    k_gate<<<NE / 256, 256, 0, stream>>>(motif, es, Pab, gw1, gb1, gw2, gb2,
                                         g_s);
    k_deg<<<(NN + 3) / 4, 256, 0, stream>>>(rowstart, count, g_s, dinv);
    k_wnorm<<<NE / 256, 256, 0, stream>>>(es, dinv, g_s);

    // layer 0
    k_conv_gemm<<<(NN + 127) / 128, 256, 0, stream>>>(x, cw, xwb);
    k_aggr<<<(NN + 3) / 4, 256, 0, stream>>>(rowstart, count, es, g_s, xwb,
                                             dinv, x, xc, cb, lg, lb);
    // layer 1
    k_conv_gemm<<<(NN + 127) / 128, 256, 0, stream>>>(xc, cw + IND * IND, xwb);
    k_aggr<<<(NN + 3) / 4, 256, 0, stream>>>(rowstart, count, es, g_s, xwb,
                                             dinv, xc, xc, cb + IND, lg + IND,
                                             lb + IND);

    k_head<<<(NN + 127) / 128, 256, 0, stream>>>(xc, hw, hb, out);
}

// Round 8
// 778.194 us; speedup vs baseline: 1.4433x; 1.1078x over previous
//
#include <hip/hip_runtime.h>
#include <cstdint>
#include <cstddef>

#define NN 100000
#define NE 1600000
#define IND 128
#define OUTD 64
#define MDIM 16
#define GHID 64
#define NPART 12500  // NN / 8 XCDs

// ---- bf16 helpers (RNE pack, exact unpack) --------------------------------
__device__ inline unsigned f2bf_pack(float a, float b) {
    unsigned ua = __float_as_uint(a);
    unsigned ub = __float_as_uint(b);
    unsigned ra = (ua + 0x7fffu + ((ua >> 16) & 1u)) >> 16;
    unsigned rb = (ub + 0x7fffu + ((ub >> 16) & 1u)) >> 16;
    return ra | (rb << 16);
}
__device__ inline float2 bf2x(unsigned u) {
    return make_float2(__uint_as_float(u << 16),
                       __uint_as_float(u & 0xffff0000u));
}

// ---------------- edge-index dtype detection (int32 vs int64) --------------
__global__ __launch_bounds__(64) void k_detect(const void* ei, int* flag) {
    const unsigned long long* p = (const unsigned long long*)ei;
    int i = threadIdx.x;
    unsigned long long v = p[(size_t)i * (NE / 64)];
    bool hi0 = (v >> 32) == 0ull;
    unsigned long long b = __ballot(hi0);
    if (i == 0) *flag = (b == ~0ull) ? 1 : 0;  // all high dwords zero -> int64
}

__global__ __launch_bounds__(256) void k_init(int* count) {
    int n = blockIdx.x * 256 + threadIdx.x;
    if (n < NN) count[n] = 0;
}

// ---------------- dst histogram straight from raw ei -----------------------
__global__ __launch_bounds__(256) void k_hist(const void* __restrict__ ei,
                                              const int* __restrict__ flag,
                                              int* __restrict__ count) {
    int e = blockIdx.x * 256 + threadIdx.x;
    if (e >= NE) return;
    int d = (*flag) ? (int)((const long long*)ei)[NE + e]
                    : ((const int*)ei)[NE + e];
    atomicAdd(&count[d], 1);
}

// ---------------- Pa/Pb precompute (bf16): row = [Pa(64) | Pb(64)] ---------
// LDS-staged weights (broadcast reads: cg = tid>>6 wave-uniform) + padded
// LDS transpose for fully-coalesced output stores. Round-7 version had
// per-lane divergent weight pointers + stride-64B scatter stores: 110 us
// for 8 us of rooflined work.
__global__ __launch_bounds__(256) void k_pre(const float* __restrict__ motif,
                                             const float* __restrict__ w1,
                                             unsigned* __restrict__ Pab) {
    __shared__ float sw[16][128];      // [k][col] col<64->W1a row k; else W1b
    __shared__ unsigned sout[64][65];  // +1 pad: conflict-free transpose
    int tid = threadIdx.x;
#pragma unroll
    for (int i = 0; i < 8; i++) {
        int flat = tid + 256 * i;  // 0..2047
        int k = flat >> 7, c = flat & 127;
        int row = (c < 64) ? k : (16 + k);
        sw[k][c] = w1[row * 64 + (c & 63)];
    }
    __syncthreads();
    int lane = tid & 63;
    int cg = tid >> 6;  // wave-uniform column group 0..3
    int n = blockIdx.x * 64 + lane;
    float m[MDIM];
    if (n < NN) {
        const float4* mr = (const float4*)(motif + (size_t)n * MDIM);
#pragma unroll
        for (int i = 0; i < 4; i++) {
            float4 t = mr[i];
            m[4 * i] = t.x; m[4 * i + 1] = t.y;
            m[4 * i + 2] = t.z; m[4 * i + 3] = t.w;
        }
    } else {
#pragma unroll
        for (int i = 0; i < MDIM; i++) m[i] = 0.0f;
    }
    float h[32];
#pragma unroll
    for (int j = 0; j < 32; j++) h[j] = 0.0f;
#pragma unroll
    for (int k = 0; k < MDIM; k++) {
        float f = m[k];
        const float* wr = &sw[k][cg * 32];
#pragma unroll
        for (int j = 0; j < 32; j++) h[j] = fmaf(f, wr[j], h[j]);
    }
#pragma unroll
    for (int jj = 0; jj < 16; jj++)
        sout[lane][cg * 16 + jj] = f2bf_pack(h[2 * jj], h[2 * jj + 1]);
    __syncthreads();
    int base = blockIdx.x * 64;
#pragma unroll
    for (int i = 0; i < 16; i++) {
        int flat = i * 256 + tid;  // 0..4095
        int row = flat >> 6, col = flat & 63;
        int nn = base + row;
        if (nn < NN) Pab[(size_t)nn * 64 + col] = sout[row][col];
    }
}

// ---------------- counting-sort scan (exclusive prefix of count) -----------
__global__ __launch_bounds__(256) void k_scan1(const int* __restrict__ count,
                                               int* __restrict__ rs,
                                               int* __restrict__ bsum) {
    __shared__ int sd[256];
    int tid = threadIdx.x;
    int base = blockIdx.x * 2048 + tid * 8;
    int loc[8]; int s = 0;
#pragma unroll
    for (int i = 0; i < 8; i++) {
        int idx = base + i;
        int v = (idx < NN) ? count[idx] : 0;
        loc[i] = s; s += v;
    }
    sd[tid] = s; __syncthreads();
    for (int off = 1; off < 256; off <<= 1) {
        int t = (tid >= off) ? sd[tid - off] : 0;
        __syncthreads();
        sd[tid] += t;
        __syncthreads();
    }
    int texcl = sd[tid] - s;
    if (tid == 255) bsum[blockIdx.x] = sd[255];
#pragma unroll
    for (int i = 0; i < 8; i++) {
        int idx = base + i;
        if (idx < NN) rs[idx] = texcl + loc[i];
    }
}

__global__ __launch_bounds__(64) void k_scan2(const int* __restrict__ bsum,
                                              int* __restrict__ boffs) {
    int tid = threadIdx.x;
    int v = (tid < 49) ? bsum[tid] : 0;
    int x = v;
#pragma unroll
    for (int off = 1; off < 64; off <<= 1) {
        int t = __shfl_up(x, off, 64);
        if (tid >= off) x += t;
    }
    boffs[tid] = x - v;  // exclusive
}

__global__ __launch_bounds__(256) void k_scan3(int* __restrict__ rs,
                                               const int* __restrict__ boffs,
                                               int* __restrict__ cursor) {
    int i = blockIdx.x * 256 + threadIdx.x;
    if (i < NN) {
        int v = rs[i] + boffs[i >> 11];
        rs[i] = v;
        cursor[i] = v;
    }
}

// ---------------- fill CSR, XCD-partitioned by dst range -------------------
__global__ __launch_bounds__(256) void k_fill(const void* __restrict__ ei,
                                              const int* __restrict__ flag,
                                              int* __restrict__ cursor,
                                              int2* __restrict__ es) {
    int p = blockIdx.x & 7;
    int base = (blockIdx.x >> 3) * 2048;
    bool is64 = (*flag) != 0;
#pragma unroll 1
    for (int it = 0; it < 8; it++) {
        int e = base + it * 256 + threadIdx.x;
        if (e >= NE) break;
        int d = is64 ? (int)((const long long*)ei)[NE + e]
                     : ((const int*)ei)[NE + e];
        if ((unsigned)d / NPART != (unsigned)p) continue;
        int s = is64 ? (int)((const long long*)ei)[e] : ((const int*)ei)[e];
        int pos = atomicAdd(&cursor[d], 1);
        es[pos] = make_int2(s, d);
    }
}

// ---------------- edge gate MLP in dst-sorted order ------------------------
// h = Pa[s] + Pb[d] + b1 + |mu-mv|@W1c + (mu*mv)@W1d   (Pa/Pb in bf16)
__global__ __launch_bounds__(256, 4) void k_gate(
    const float* __restrict__ motif, const int2* __restrict__ es,
    const unsigned* __restrict__ Pab, const float* __restrict__ w1,
    const float* __restrict__ b1, const float* __restrict__ w2,
    const float* __restrict__ b2, float* __restrict__ g_s) {
    int e = blockIdx.x * 256 + threadIdx.x;
    if (e >= NE) return;
    int2 sd = es[e];
    int s = sd.x, d = sd.y;
    float mu[MDIM], mv[MDIM];
    const float4* ms = (const float4*)(motif + (size_t)s * MDIM);
    const float4* mdp = (const float4*)(motif + (size_t)d * MDIM);
#pragma unroll
    for (int q = 0; q < 4; q++) {
        float4 a = ms[q], b = mdp[q];
        mu[4 * q] = a.x; mu[4 * q + 1] = a.y; mu[4 * q + 2] = a.z; mu[4 * q + 3] = a.w;
        mv[4 * q] = b.x; mv[4 * q + 1] = b.y; mv[4 * q + 2] = b.z; mv[4 * q + 3] = b.w;
    }
    const unsigned* pas = Pab + (size_t)s * 64;        // Pa: uints 0..31
    const unsigned* pbd = Pab + (size_t)d * 64 + 32;   // Pb: uints 32..63
    const float* w1c = w1 + 2 * MDIM * GHID;
    const float* w1d = w1 + 3 * MDIM * GHID;
    float g = b2[0];
#pragma unroll 1
    for (int jh = 0; jh < 2; jh++) {
        float h[32];
#pragma unroll
        for (int jj = 0; jj < 16; jj++) {
            float2 a = bf2x(pas[jh * 16 + jj]);
            float2 b = bf2x(pbd[jh * 16 + jj]);
            h[2 * jj] = a.x + b.x + b1[jh * 32 + 2 * jj];
            h[2 * jj + 1] = a.y + b.y + b1[jh * 32 + 2 * jj + 1];
        }
#pragma unroll 1
        for (int k = 0; k < MDIM; k++) {
            float f0 = mu[k], f1 = mv[k];
            float f2 = fabsf(f0 - f1), f3 = f0 * f1;
            const float* wc = w1c + k * GHID + jh * 32;
            const float* wd = w1d + k * GHID + jh * 32;
#pragma unroll
            for (int j = 0; j < 32; j++) {
                h[j] = fmaf(f2, wc[j], h[j]);
                h[j] = fmaf(f3, wd[j], h[j]);
            }
        }
        const float* w2p = w2 + jh * 32;
#pragma unroll
        for (int j = 0; j < 32; j++) g = fmaf(fmaxf(h[j], 0.0f), w2p[j], g);
    }
    g_s[e] = 1.0f / (1.0f + __expf(-g));
}

// ---------------- deg = 1 + row-sum of sorted gates -> dinv (wave/node) ----
__global__ __launch_bounds__(256) void k_deg(const int* __restrict__ rowstart,
                                             const int* __restrict__ count,
                                             const float* __restrict__ g_s,
                                             float* __restrict__ dinv) {
    int n = blockIdx.x * 4 + (threadIdx.x >> 6);
    int lane = threadIdx.x & 63;
    if (n >= NN) return;
    int a = rowstart[n], cnt = count[n];
    float sum = 0.0f;
    for (int c = lane; c < cnt; c += 64) sum += g_s[a + c];
#pragma unroll
    for (int m = 1; m < 64; m <<= 1) sum += __shfl_xor(sum, m, 64);
    if (lane == 0) dinv[n] = rsqrtf(1.0f + sum);
}

// ---------------- g_s[e] *= dinv[src]*dinv[dst] (in-place, coalesced) ------
__global__ __launch_bounds__(256) void k_wnorm(const int2* __restrict__ es,
                                               const float* __restrict__ dinv,
                                               float* __restrict__ g_s) {
    int e = blockIdx.x * 256 + threadIdx.x;
    if (e >= NE) return;
    int2 sd = es[e];
    g_s[e] *= dinv[sd.x] * dinv[sd.y];
}

// ---------------- xw = A @ W (128x128), output bf16-packed -----------------
__global__ __launch_bounds__(256) void k_conv_gemm(
    const float* __restrict__ A, const float* __restrict__ Bw,
    unsigned* __restrict__ xwb) {
    __shared__ float sB[IND * IND];  // 64 KB
    int tid = threadIdx.x;
    {
        const float4* B4 = (const float4*)Bw;
        float4* s4 = (float4*)sB;
#pragma unroll
        for (int i = 0; i < 16; i++) s4[tid + 256 * i] = B4[tid + 256 * i];
    }
    __syncthreads();
    int cg = tid >> 5, rs = tid & 31;
    int row0 = blockIdx.x * 128 + rs * 4;
    int col0 = cg * 16;
    float acc[4][16];
#pragma unroll
    for (int j = 0; j < 4; j++)
#pragma unroll
        for (int c = 0; c < 16; c++) acc[j][c] = 0.0f;
    for (int k = 0; k < IND; k += 4) {
        float4 a[4];
#pragma unroll
        for (int j = 0; j < 4; j++) {
            int r = row0 + j;
            a[j] = (r < NN) ? *(const float4*)(A + (size_t)r * IND + k)
                            : make_float4(0.f, 0.f, 0.f, 0.f);
        }
#pragma unroll
        for (int kk = 0; kk < 4; kk++) {
            float b[16];
            const float4* bb = (const float4*)(sB + (k + kk) * IND + col0);
#pragma unroll
            for (int q = 0; q < 4; q++) {
                float4 t = bb[q];
                b[4 * q] = t.x; b[4 * q + 1] = t.y; b[4 * q + 2] = t.z; b[4 * q + 3] = t.w;
            }
#pragma unroll
            for (int j = 0; j < 4; j++) {
                float av = (kk == 0) ? a[j].x : (kk == 1) ? a[j].y : (kk == 2) ? a[j].z : a[j].w;
#pragma unroll
                for (int c = 0; c < 16; c++) acc[j][c] = fmaf(av, b[c], acc[j][c]);
            }
        }
    }
#pragma unroll
    for (int j = 0; j < 4; j++) {
        int r = row0 + j;
        if (r >= NN) continue;
        unsigned* xo = xwb + (size_t)r * 64 + col0 / 2;
#pragma unroll
        for (int q = 0; q < 8; q++)
            xo[q] = f2bf_pack(acc[j][2 * q], acc[j][2 * q + 1]);
    }
}

// ---------------- fused gather(bf16) + bias + LN + relu + residual ---------
__global__ __launch_bounds__(256) void k_aggr(
    const int* __restrict__ rowstart, const int* __restrict__ count,
    const int2* __restrict__ es, const float* __restrict__ w_s,
    const unsigned* __restrict__ xwb, const float* __restrict__ dinv,
    const float* __restrict__ xold, float* __restrict__ xnew,
    const float* __restrict__ cb, const float* __restrict__ lg,
    const float* __restrict__ lb) {
    int n = blockIdx.x * 4 + (threadIdx.x >> 6);
    int lane = threadIdx.x & 63;
    if (n >= NN) return;
    float dn = dinv[n];
    float2 acc = bf2x(xwb[(size_t)n * 64 + lane]);  // self-loop
    acc.x *= dn * dn; acc.y *= dn * dn;
    int start = rowstart[n], cnt = count[n];
    for (int c = 0; c < cnt; c += 64) {
        int rem = cnt - c;
        int sv = 0; float wv = 0.0f;
        if (lane < rem) {
            sv = es[start + c + lane].x;
            wv = w_s[start + c + lane];
        }
        int m = rem < 64 ? rem : 64;
        int j = 0;
        for (; j + 4 <= m; j += 4) {  // 4 independent loads in flight
            int s0 = __shfl(sv, j, 64), s1 = __shfl(sv, j + 1, 64);
            int s2 = __shfl(sv, j + 2, 64), s3 = __shfl(sv, j + 3, 64);
            float w0 = __shfl(wv, j, 64), w1 = __shfl(wv, j + 1, 64);
            float w2 = __shfl(wv, j + 2, 64), w3 = __shfl(wv, j + 3, 64);
            unsigned u0 = xwb[(size_t)s0 * 64 + lane];
            unsigned u1 = xwb[(size_t)s1 * 64 + lane];
            unsigned u2 = xwb[(size_t)s2 * 64 + lane];
            unsigned u3 = xwb[(size_t)s3 * 64 + lane];
            float2 v0 = bf2x(u0), v1 = bf2x(u1), v2 = bf2x(u2), v3 = bf2x(u3);
            acc.x = fmaf(w0, v0.x, acc.x); acc.y = fmaf(w0, v0.y, acc.y);
            acc.x = fmaf(w1, v1.x, acc.x); acc.y = fmaf(w1, v1.y, acc.y);
            acc.x = fmaf(w2, v2.x, acc.x); acc.y = fmaf(w2, v2.y, acc.y);
            acc.x = fmaf(w3, v3.x, acc.x); acc.y = fmaf(w3, v3.y, acc.y);
        }
        for (; j < m; j++) {
            int s = __shfl(sv, j, 64);
            float w = __shfl(wv, j, 64);
            float2 v = bf2x(xwb[(size_t)s * 64 + lane]);
            acc.x = fmaf(w, v.x, acc.x); acc.y = fmaf(w, v.y, acc.y);
        }
    }
    float2 cbv = ((const float2*)cb)[lane];
    acc.x += cbv.x; acc.y += cbv.y;
    float s1 = acc.x + acc.y, s2 = acc.x * acc.x + acc.y * acc.y;
#pragma unroll
    for (int mm = 1; mm < 64; mm <<= 1) {
        s1 += __shfl_xor(s1, mm, 64);
        s2 += __shfl_xor(s2, mm, 64);
    }
    float mean = s1 * (1.0f / 128.0f);
    float var = s2 * (1.0f / 128.0f) - mean * mean;
    float rstd = rsqrtf(var + 1e-5f);
    float2 lgv = ((const float2*)lg)[lane];
    float2 lbv = ((const float2*)lb)[lane];
    float y0 = fmaxf((acc.x - mean) * rstd * lgv.x + lbv.x, 0.0f);
    float y1 = fmaxf((acc.y - mean) * rstd * lgv.y + lbv.y, 0.0f);
    float2 xo = ((const float2*)xold)[(size_t)n * 64 + lane];
    ((float2*)xnew)[(size_t)n * 64 + lane] =
        make_float2(xo.x + y0, xo.y + y1);
}

// ---------------- head: out = A @ head_w + head_b --------------------------
__global__ __launch_bounds__(256) void k_head(
    const float* __restrict__ A, const float* __restrict__ Bw,
    const float* __restrict__ bias, float* __restrict__ out) {
    __shared__ float sB[IND * OUTD];  // 32 KB
    int tid = threadIdx.x;
    {
        const float4* B4 = (const float4*)Bw;
        float4* s4 = (float4*)sB;
#pragma unroll
        for (int i = 0; i < 8; i++) s4[tid + 256 * i] = B4[tid + 256 * i];
    }
    __syncthreads();
    int cg = tid >> 6, rs = tid & 63;
    int row0 = blockIdx.x * 128 + rs * 2;
    int col0 = cg * 16;
    float acc[2][16];
#pragma unroll
    for (int j = 0; j < 2; j++)
#pragma unroll
        for (int c = 0; c < 16; c++) acc[j][c] = 0.0f;
    for (int k = 0; k < IND; k += 4) {
        float4 a[2];
#pragma unroll
        for (int j = 0; j < 2; j++) {
            int r = row0 + j;
            a[j] = (r < NN) ? *(const float4*)(A + (size_t)r * IND + k)
                            : make_float4(0.f, 0.f, 0.f, 0.f);
        }
#pragma unroll
        for (int kk = 0; kk < 4; kk++) {
            float b[16];
            const float4* bb = (const float4*)(sB + (k + kk) * OUTD + col0);
#pragma unroll
            for (int q = 0; q < 4; q++) {
                float4 t = bb[q];
                b[4 * q] = t.x; b[4 * q + 1] = t.y; b[4 * q + 2] = t.z; b[4 * q + 3] = t.w;
            }
#pragma unroll
            for (int j = 0; j < 2; j++) {
                float av = (kk == 0) ? a[j].x : (kk == 1) ? a[j].y : (kk == 2) ? a[j].z : a[j].w;
#pragma unroll
                for (int c = 0; c < 16; c++) acc[j][c] = fmaf(av, b[c], acc[j][c]);
            }
        }
    }
#pragma unroll
    for (int j = 0; j < 2; j++) {
        int r = row0 + j;
        if (r >= NN) continue;
        float* op = out + (size_t)r * OUTD + col0;
#pragma unroll
        for (int q = 0; q < 4; q++) {
            float4 bs = *(const float4*)(bias + col0 + 4 * q);
            *(float4*)(op + 4 * q) =
                make_float4(acc[j][4 * q] + bs.x, acc[j][4 * q + 1] + bs.y,
                            acc[j][4 * q + 2] + bs.z, acc[j][4 * q + 3] + bs.w);
        }
    }
}

extern "C" void kernel_launch(void* const* d_in, const int* in_sizes, int n_in,
                              void* d_out, int out_size, void* d_ws,
                              size_t ws_size, hipStream_t stream) {
    const float* x = (const float*)d_in[0];
    const float* motif = (const float*)d_in[1];
    const void* ei = d_in[2];
    const float* gw1 = (const float*)d_in[3];
    const float* gb1 = (const float*)d_in[4];
    const float* gw2 = (const float*)d_in[5];
    const float* gb2 = (const float*)d_in[6];
    const float* cw = (const float*)d_in[7];   // [2,128,128]
    const float* cb = (const float*)d_in[8];   // [2,128]
    const float* lg = (const float*)d_in[9];
    const float* lb = (const float*)d_in[10];
    const float* hw = (const float*)d_in[11];  // [128,64]
    const float* hb = (const float*)d_in[12];
    float* out = (float*)d_out;

    float* ws = (float*)d_ws;
    size_t o = 0;
    float* dinv = ws + o; o += NN;
    int* flag = (int*)(ws + o); o += 64;
    int* count = (int*)(ws + o); o += NN;
    int* rowstart = (int*)(ws + o); o += NN;
    int* cursor = (int*)(ws + o); o += NN;
    int* bsum = (int*)(ws + o); o += 64;
    int* boffs = (int*)(ws + o); o += 64;
    int2* es = (int2*)(ws + o); o += 2 * (size_t)NE;
    float* g_s = ws + o; o += NE;
    unsigned* xwb = (unsigned*)(ws + o); o += (size_t)NN * 64;  // bf16 xw, aliases Pab
    float* xc = ws + o; o += (size_t)NN * IND;

    unsigned* Pab = xwb;  // alias: Pab dead before first k_conv_gemm writes xwb

    k_detect<<<1, 64, 0, stream>>>(ei, flag);
    k_init<<<(NN + 255) / 256, 256, 0, stream>>>(count);
    k_hist<<<NE / 256, 256, 0, stream>>>(ei, flag, count);
    k_pre<<<(NN + 63) / 64, 256, 0, stream>>>(motif, gw1, Pab);

    // counting sort by dst -> CSR (shared by both layers)
    k_scan1<<<(NN + 2047) / 2048, 256, 0, stream>>>(count, rowstart, bsum);
    k_scan2<<<1, 64, 0, stream>>>(bsum, boffs);
    k_scan3<<<(NN + 255) / 256, 256, 0, stream>>>(rowstart, boffs, cursor);
    // XCD-partitioned fill: 8 partitions x ceil(NE/2048) chunks
    k_fill<<<8 * ((NE + 2047) / 2048), 256, 0, stream>>>(ei, flag, cursor, es);

    // gate in dst-sorted order, then deg, then normalize weights in place
    k_gate<<<NE / 256, 256, 0, stream>>>(motif, es, Pab, gw1, gb1, gw2, gb2,
                                         g_s);
    k_deg<<<(NN + 3) / 4, 256, 0, stream>>>(rowstart, count, g_s, dinv);
    k_wnorm<<<NE / 256, 256, 0, stream>>>(es, dinv, g_s);

    // layer 0
    k_conv_gemm<<<(NN + 127) / 128, 256, 0, stream>>>(x, cw, xwb);
    k_aggr<<<(NN + 3) / 4, 256, 0, stream>>>(rowstart, count, es, g_s, xwb,
                                             dinv, x, xc, cb, lg, lb);
    // layer 1
    k_conv_gemm<<<(NN + 127) / 128, 256, 0, stream>>>(xc, cw + IND * IND, xwb);
    k_aggr<<<(NN + 3) / 4, 256, 0, stream>>>(rowstart, count, es, g_s, xwb,
                                             dinv, xc, xc, cb + IND, lg + IND,
                                             lb + IND);

    k_head<<<(NN + 127) / 128, 256, 0, stream>>>(xc, hw, hb, out);
}

// Round 9
// 624.848 us; speedup vs baseline: 1.7975x; 1.2454x over previous
//
#include <hip/hip_runtime.h>
#include <cstdint>
#include <cstddef>

#define NN 100000
#define NE 1600000
#define IND 128
#define OUTD 64
#define MDIM 16
#define GHID 64
#define NPART 12500  // NN / 8 XCDs

typedef __attribute__((ext_vector_type(8))) short bf8_t;
typedef __attribute__((ext_vector_type(4))) float f4_t;
typedef unsigned short ushort_t;

// ---- bf16 helpers (RNE pack, exact unpack) --------------------------------
__device__ inline unsigned f2bf_pack(float a, float b) {
    unsigned ua = __float_as_uint(a);
    unsigned ub = __float_as_uint(b);
    unsigned ra = (ua + 0x7fffu + ((ua >> 16) & 1u)) >> 16;
    unsigned rb = (ub + 0x7fffu + ((ub >> 16) & 1u)) >> 16;
    return ra | (rb << 16);
}
__device__ inline ushort_t f2bf1(float f) {
    unsigned u = __float_as_uint(f);
    return (ushort_t)((u + 0x7fffu + ((u >> 16) & 1u)) >> 16);
}
__device__ inline float2 bf2x(unsigned u) {
    return make_float2(__uint_as_float(u << 16),
                       __uint_as_float(u & 0xffff0000u));
}

// ---------------- edge-index dtype detection (int32 vs int64) --------------
__global__ __launch_bounds__(64) void k_detect(const void* ei, int* flag) {
    const unsigned long long* p = (const unsigned long long*)ei;
    int i = threadIdx.x;
    unsigned long long v = p[(size_t)i * (NE / 64)];
    bool hi0 = (v >> 32) == 0ull;
    unsigned long long b = __ballot(hi0);
    if (i == 0) *flag = (b == ~0ull) ? 1 : 0;  // all high dwords zero -> int64
}

__global__ __launch_bounds__(256) void k_init(int* count) {
    int n = blockIdx.x * 256 + threadIdx.x;
    if (n < NN) count[n] = 0;
}

// ---------------- dst histogram straight from raw ei -----------------------
__global__ __launch_bounds__(256) void k_hist(const void* __restrict__ ei,
                                              const int* __restrict__ flag,
                                              int* __restrict__ count) {
    int e = blockIdx.x * 256 + threadIdx.x;
    if (e >= NE) return;
    int d = (*flag) ? (int)((const long long*)ei)[NE + e]
                    : ((const int*)ei)[NE + e];
    atomicAdd(&count[d], 1);
}

// ---------------- x fp32 -> bf16 packed ------------------------------------
__global__ __launch_bounds__(256) void k_cvt(const float* __restrict__ x,
                                             unsigned* __restrict__ xb) {
    int i = blockIdx.x * 256 + threadIdx.x;  // one float4 -> uint2
    if (i >= NN * 32) return;
    float4 v = ((const float4*)x)[i];
    ((uint2*)xb)[i] = make_uint2(f2bf_pack(v.x, v.y), f2bf_pack(v.z, v.w));
}

// ---------------- pack conv/head weights into MFMA B-fragment order --------
// btf layout: [conv L0: 8nt x 4kk x 64lane x 4uint][conv L1: same][head: 4nt..]
// lane frag element j (0..7): B[k = kk*32 + (lane>>4)*8 + j][n = nt*16 + (lane&15)]
__global__ __launch_bounds__(256) void k_prep(const float* __restrict__ cw,
                                              const float* __restrict__ hw,
                                              unsigned* __restrict__ btf) {
    int i = blockIdx.x * 256 + threadIdx.x;
    if (i >= 20480) return;
    const float* W;
    int ncols, local;
    if (i < 16384) { W = cw + (i >> 13) * 16384; ncols = 128; local = i & 8191; }
    else { W = hw; ncols = 64; local = i - 16384; }
    int w = local & 3;
    int lane = (local >> 2) & 63;
    int kk = (local >> 8) & 3;
    int nt = local >> 10;
    int n = nt * 16 + (lane & 15);
    int k = kk * 32 + (lane >> 4) * 8 + 2 * w;
    btf[i] = f2bf_pack(W[k * ncols + n], W[(k + 1) * ncols + n]);
}

// ---------------- Pa/Pb precompute (bf16): row = [Pa(64) | Pb(64)] ---------
__global__ __launch_bounds__(256) void k_pre(const float* __restrict__ motif,
                                             const float* __restrict__ w1,
                                             unsigned* __restrict__ Pab) {
    __shared__ float sw[16][128];      // [k][col] col<64->W1a row k; else W1b
    __shared__ unsigned sout[64][65];  // +1 pad: conflict-free transpose
    int tid = threadIdx.x;
#pragma unroll
    for (int i = 0; i < 8; i++) {
        int flat = tid + 256 * i;  // 0..2047
        int k = flat >> 7, c = flat & 127;
        int row = (c < 64) ? k : (16 + k);
        sw[k][c] = w1[row * 64 + (c & 63)];
    }
    __syncthreads();
    int lane = tid & 63;
    int cg = tid >> 6;  // wave-uniform column group 0..3
    int n = blockIdx.x * 64 + lane;
    float m[MDIM];
    if (n < NN) {
        const float4* mr = (const float4*)(motif + (size_t)n * MDIM);
#pragma unroll
        for (int i = 0; i < 4; i++) {
            float4 t = mr[i];
            m[4 * i] = t.x; m[4 * i + 1] = t.y;
            m[4 * i + 2] = t.z; m[4 * i + 3] = t.w;
        }
    } else {
#pragma unroll
        for (int i = 0; i < MDIM; i++) m[i] = 0.0f;
    }
    float h[32];
#pragma unroll
    for (int j = 0; j < 32; j++) h[j] = 0.0f;
#pragma unroll
    for (int k = 0; k < MDIM; k++) {
        float f = m[k];
        const float* wr = &sw[k][cg * 32];
#pragma unroll
        for (int j = 0; j < 32; j++) h[j] = fmaf(f, wr[j], h[j]);
    }
#pragma unroll
    for (int jj = 0; jj < 16; jj++)
        sout[lane][cg * 16 + jj] = f2bf_pack(h[2 * jj], h[2 * jj + 1]);
    __syncthreads();
    int base = blockIdx.x * 64;
#pragma unroll
    for (int i = 0; i < 16; i++) {
        int flat = i * 256 + tid;  // 0..4095
        int row = flat >> 6, col = flat & 63;
        int nn = base + row;
        if (nn < NN) Pab[(size_t)nn * 64 + col] = sout[row][col];
    }
}

// ---------------- counting-sort scan (exclusive prefix of count) -----------
__global__ __launch_bounds__(256) void k_scan1(const int* __restrict__ count,
                                               int* __restrict__ rs,
                                               int* __restrict__ bsum) {
    __shared__ int sd[256];
    int tid = threadIdx.x;
    int base = blockIdx.x * 2048 + tid * 8;
    int loc[8]; int s = 0;
#pragma unroll
    for (int i = 0; i < 8; i++) {
        int idx = base + i;
        int v = (idx < NN) ? count[idx] : 0;
        loc[i] = s; s += v;
    }
    sd[tid] = s; __syncthreads();
    for (int off = 1; off < 256; off <<= 1) {
        int t = (tid >= off) ? sd[tid - off] : 0;
        __syncthreads();
        sd[tid] += t;
        __syncthreads();
    }
    int texcl = sd[tid] - s;
    if (tid == 255) bsum[blockIdx.x] = sd[255];
#pragma unroll
    for (int i = 0; i < 8; i++) {
        int idx = base + i;
        if (idx < NN) rs[idx] = texcl + loc[i];
    }
}

__global__ __launch_bounds__(64) void k_scan2(const int* __restrict__ bsum,
                                              int* __restrict__ boffs) {
    int tid = threadIdx.x;
    int v = (tid < 49) ? bsum[tid] : 0;
    int x = v;
#pragma unroll
    for (int off = 1; off < 64; off <<= 1) {
        int t = __shfl_up(x, off, 64);
        if (tid >= off) x += t;
    }
    boffs[tid] = x - v;  // exclusive
}

__global__ __launch_bounds__(256) void k_scan3(int* __restrict__ rs,
                                               const int* __restrict__ boffs,
                                               int* __restrict__ cursor) {
    int i = blockIdx.x * 256 + threadIdx.x;
    if (i < NN) {
        int v = rs[i] + boffs[i >> 11];
        rs[i] = v;
        cursor[i] = v;
    }
}

// ---------------- fill CSR, XCD-partitioned by dst range -------------------
__global__ __launch_bounds__(256) void k_fill(const void* __restrict__ ei,
                                              const int* __restrict__ flag,
                                              int* __restrict__ cursor,
                                              int2* __restrict__ es) {
    int p = blockIdx.x & 7;
    int base = (blockIdx.x >> 3) * 2048;
    bool is64 = (*flag) != 0;
#pragma unroll 1
    for (int it = 0; it < 8; it++) {
        int e = base + it * 256 + threadIdx.x;
        if (e >= NE) break;
        int d = is64 ? (int)((const long long*)ei)[NE + e]
                     : ((const int*)ei)[NE + e];
        if ((unsigned)d / NPART != (unsigned)p) continue;
        int s = is64 ? (int)((const long long*)ei)[e] : ((const int*)ei)[e];
        int pos = atomicAdd(&cursor[d], 1);
        es[pos] = make_int2(s, d);
    }
}

// ---------------- edge gate MLP in dst-sorted order ------------------------
__global__ __launch_bounds__(256, 4) void k_gate(
    const float* __restrict__ motif, const int2* __restrict__ es,
    const unsigned* __restrict__ Pab, const float* __restrict__ w1,
    const float* __restrict__ b1, const float* __restrict__ w2,
    const float* __restrict__ b2, float* __restrict__ g_s) {
    int e = blockIdx.x * 256 + threadIdx.x;
    if (e >= NE) return;
    int2 sd = es[e];
    int s = sd.x, d = sd.y;
    float mu[MDIM], mv[MDIM];
    const float4* ms = (const float4*)(motif + (size_t)s * MDIM);
    const float4* mdp = (const float4*)(motif + (size_t)d * MDIM);
#pragma unroll
    for (int q = 0; q < 4; q++) {
        float4 a = ms[q], b = mdp[q];
        mu[4 * q] = a.x; mu[4 * q + 1] = a.y; mu[4 * q + 2] = a.z; mu[4 * q + 3] = a.w;
        mv[4 * q] = b.x; mv[4 * q + 1] = b.y; mv[4 * q + 2] = b.z; mv[4 * q + 3] = b.w;
    }
    const unsigned* pas = Pab + (size_t)s * 64;        // Pa: uints 0..31
    const unsigned* pbd = Pab + (size_t)d * 64 + 32;   // Pb: uints 32..63
    const float* w1c = w1 + 2 * MDIM * GHID;
    const float* w1d = w1 + 3 * MDIM * GHID;
    float g = b2[0];
#pragma unroll 1
    for (int jh = 0; jh < 2; jh++) {
        float h[32];
#pragma unroll
        for (int jj = 0; jj < 16; jj++) {
            float2 a = bf2x(pas[jh * 16 + jj]);
            float2 b = bf2x(pbd[jh * 16 + jj]);
            h[2 * jj] = a.x + b.x + b1[jh * 32 + 2 * jj];
            h[2 * jj + 1] = a.y + b.y + b1[jh * 32 + 2 * jj + 1];
        }
#pragma unroll 1
        for (int k = 0; k < MDIM; k++) {
            float f0 = mu[k], f1 = mv[k];
            float f2 = fabsf(f0 - f1), f3 = f0 * f1;
            const float* wc = w1c + k * GHID + jh * 32;
            const float* wd = w1d + k * GHID + jh * 32;
#pragma unroll
            for (int j = 0; j < 32; j++) {
                h[j] = fmaf(f2, wc[j], h[j]);
                h[j] = fmaf(f3, wd[j], h[j]);
            }
        }
        const float* w2p = w2 + jh * 32;
#pragma unroll
        for (int j = 0; j < 32; j++) g = fmaf(fmaxf(h[j], 0.0f), w2p[j], g);
    }
    g_s[e] = 1.0f / (1.0f + __expf(-g));
}

// ---------------- deg = 1 + row-sum of sorted gates -> dinv (wave/node) ----
__global__ __launch_bounds__(256) void k_deg(const int* __restrict__ rowstart,
                                             const int* __restrict__ count,
                                             const float* __restrict__ g_s,
                                             float* __restrict__ dinv) {
    int n = blockIdx.x * 4 + (threadIdx.x >> 6);
    int lane = threadIdx.x & 63;
    if (n >= NN) return;
    int a = rowstart[n], cnt = count[n];
    float sum = 0.0f;
    for (int c = lane; c < cnt; c += 64) sum += g_s[a + c];
#pragma unroll
    for (int m = 1; m < 64; m <<= 1) sum += __shfl_xor(sum, m, 64);
    if (lane == 0) dinv[n] = rsqrtf(1.0f + sum);
}

// ---------------- g_s[e] *= dinv[src]*dinv[dst] (in-place, coalesced) ------
__global__ __launch_bounds__(256) void k_wnorm(const int2* __restrict__ es,
                                               const float* __restrict__ dinv,
                                               float* __restrict__ g_s) {
    int e = blockIdx.x * 256 + threadIdx.x;
    if (e >= NE) return;
    int2 sd = es[e];
    g_s[e] *= dinv[sd.x] * dinv[sd.y];
}

// ---------------- MFMA GEMM: xw_bf16 = A_bf16 @ W  (M=NN, N=128, K=128) ----
// Block = 64 rows, 4 waves: wave (w&1) -> 32-row half (2 m-tiles),
// (w>>1) -> 64-col half (4 n-tiles). B-frags from fragment-linear btf
// (coalesced L2-resident dwordx4); A-frags straight from global (a wave's
// 64 x 16B loads cover exactly 16 full 64B lines). No LDS.
__global__ __launch_bounds__(256) void k_mm_conv(
    const ushort_t* __restrict__ A, const uint4* __restrict__ btf,
    ushort_t* __restrict__ outb) {
    int w = threadIdx.x >> 6, lane = threadIdx.x & 63;
    int mh = w & 1, nh = w >> 1;
    int quad = lane >> 4, lx = lane & 15;
    int m0 = blockIdx.x * 64 + mh * 32;
    bf8_t a[2][4];
#pragma unroll
    for (int mt = 0; mt < 2; mt++) {
        int row = m0 + mt * 16 + lx;
        row = row < NN ? row : NN - 1;
#pragma unroll
        for (int kk = 0; kk < 4; kk++)
            a[mt][kk] = *(const bf8_t*)(A + (size_t)row * 128 + kk * 32 + quad * 8);
    }
    f4_t acc[2][4];
#pragma unroll
    for (int mt = 0; mt < 2; mt++)
#pragma unroll
        for (int nt = 0; nt < 4; nt++) acc[mt][nt] = (f4_t){0.f, 0.f, 0.f, 0.f};
#pragma unroll
    for (int nt = 0; nt < 4; nt++) {
        int ntg = nh * 4 + nt;
#pragma unroll
        for (int kk = 0; kk < 4; kk++) {
            union { uint4 u; bf8_t v; } bb;
            bb.u = btf[(ntg * 4 + kk) * 64 + lane];
            acc[0][nt] = __builtin_amdgcn_mfma_f32_16x16x32_bf16(
                a[0][kk], bb.v, acc[0][nt], 0, 0, 0);
            acc[1][nt] = __builtin_amdgcn_mfma_f32_16x16x32_bf16(
                a[1][kk], bb.v, acc[1][nt], 0, 0, 0);
        }
    }
#pragma unroll
    for (int mt = 0; mt < 2; mt++)
#pragma unroll
        for (int nt = 0; nt < 4; nt++) {
#pragma unroll
            for (int r = 0; r < 4; r++) {
                int row = m0 + mt * 16 + quad * 4 + r;
                if (row < NN)
                    outb[(size_t)row * 128 + (nh * 4 + nt) * 16 + lx] =
                        f2bf1(acc[mt][nt][r]);
            }
        }
}

// ---------------- MFMA GEMM head: out = A_bf16 @ head_w + head_b (N=64) ----
__global__ __launch_bounds__(256) void k_mm_head(
    const ushort_t* __restrict__ A, const uint4* __restrict__ btf,
    const float* __restrict__ bias, float* __restrict__ out) {
    int w = threadIdx.x >> 6, lane = threadIdx.x & 63;
    int mh = w & 1, nh = w >> 1;
    int quad = lane >> 4, lx = lane & 15;
    int m0 = blockIdx.x * 64 + mh * 32;
    bf8_t a[2][4];
#pragma unroll
    for (int mt = 0; mt < 2; mt++) {
        int row = m0 + mt * 16 + lx;
        row = row < NN ? row : NN - 1;
#pragma unroll
        for (int kk = 0; kk < 4; kk++)
            a[mt][kk] = *(const bf8_t*)(A + (size_t)row * 128 + kk * 32 + quad * 8);
    }
    f4_t acc[2][2];
#pragma unroll
    for (int mt = 0; mt < 2; mt++)
#pragma unroll
        for (int nt = 0; nt < 2; nt++) acc[mt][nt] = (f4_t){0.f, 0.f, 0.f, 0.f};
#pragma unroll
    for (int nt = 0; nt < 2; nt++) {
        int ntg = nh * 2 + nt;
#pragma unroll
        for (int kk = 0; kk < 4; kk++) {
            union { uint4 u; bf8_t v; } bb;
            bb.u = btf[(ntg * 4 + kk) * 64 + lane];
            acc[0][nt] = __builtin_amdgcn_mfma_f32_16x16x32_bf16(
                a[0][kk], bb.v, acc[0][nt], 0, 0, 0);
            acc[1][nt] = __builtin_amdgcn_mfma_f32_16x16x32_bf16(
                a[1][kk], bb.v, acc[1][nt], 0, 0, 0);
        }
    }
#pragma unroll
    for (int mt = 0; mt < 2; mt++)
#pragma unroll
        for (int nt = 0; nt < 2; nt++) {
            int col = (nh * 2 + nt) * 16 + lx;
            float bs = bias[col];
#pragma unroll
            for (int r = 0; r < 4; r++) {
                int row = m0 + mt * 16 + quad * 4 + r;
                if (row < NN) out[(size_t)row * 64 + col] = acc[mt][nt][r] + bs;
            }
        }
}

// ---------------- fused gather(bf16) + bias + LN + relu + residual ---------
// also emits bf16 copy of xnew (next GEMM / head input)
__global__ __launch_bounds__(256) void k_aggr(
    const int* __restrict__ rowstart, const int* __restrict__ count,
    const int2* __restrict__ es, const float* __restrict__ w_s,
    const unsigned* __restrict__ xwb, const float* __restrict__ dinv,
    const float* __restrict__ xold, float* __restrict__ xnew,
    unsigned* __restrict__ xnewb, const float* __restrict__ cb,
    const float* __restrict__ lg, const float* __restrict__ lb) {
    int n = blockIdx.x * 4 + (threadIdx.x >> 6);
    int lane = threadIdx.x & 63;
    if (n >= NN) return;
    float dn = dinv[n];
    float2 acc = bf2x(xwb[(size_t)n * 64 + lane]);  // self-loop
    acc.x *= dn * dn; acc.y *= dn * dn;
    int start = rowstart[n], cnt = count[n];
    for (int c = 0; c < cnt; c += 64) {
        int rem = cnt - c;
        int sv = 0; float wv = 0.0f;
        if (lane < rem) {
            sv = es[start + c + lane].x;
            wv = w_s[start + c + lane];
        }
        int m = rem < 64 ? rem : 64;
        int j = 0;
        for (; j + 4 <= m; j += 4) {  // 4 independent loads in flight
            int s0 = __shfl(sv, j, 64), s1 = __shfl(sv, j + 1, 64);
            int s2 = __shfl(sv, j + 2, 64), s3 = __shfl(sv, j + 3, 64);
            float w0 = __shfl(wv, j, 64), w1 = __shfl(wv, j + 1, 64);
            float w2 = __shfl(wv, j + 2, 64), w3 = __shfl(wv, j + 3, 64);
            unsigned u0 = xwb[(size_t)s0 * 64 + lane];
            unsigned u1 = xwb[(size_t)s1 * 64 + lane];
            unsigned u2 = xwb[(size_t)s2 * 64 + lane];
            unsigned u3 = xwb[(size_t)s3 * 64 + lane];
            float2 v0 = bf2x(u0), v1 = bf2x(u1), v2 = bf2x(u2), v3 = bf2x(u3);
            acc.x = fmaf(w0, v0.x, acc.x); acc.y = fmaf(w0, v0.y, acc.y);
            acc.x = fmaf(w1, v1.x, acc.x); acc.y = fmaf(w1, v1.y, acc.y);
            acc.x = fmaf(w2, v2.x, acc.x); acc.y = fmaf(w2, v2.y, acc.y);
            acc.x = fmaf(w3, v3.x, acc.x); acc.y = fmaf(w3, v3.y, acc.y);
        }
        for (; j < m; j++) {
            int s = __shfl(sv, j, 64);
            float w = __shfl(wv, j, 64);
            float2 v = bf2x(xwb[(size_t)s * 64 + lane]);
            acc.x = fmaf(w, v.x, acc.x); acc.y = fmaf(w, v.y, acc.y);
        }
    }
    float2 cbv = ((const float2*)cb)[lane];
    acc.x += cbv.x; acc.y += cbv.y;
    float s1 = acc.x + acc.y, s2 = acc.x * acc.x + acc.y * acc.y;
#pragma unroll
    for (int mm = 1; mm < 64; mm <<= 1) {
        s1 += __shfl_xor(s1, mm, 64);
        s2 += __shfl_xor(s2, mm, 64);
    }
    float mean = s1 * (1.0f / 128.0f);
    float var = s2 * (1.0f / 128.0f) - mean * mean;
    float rstd = rsqrtf(var + 1e-5f);
    float2 lgv = ((const float2*)lg)[lane];
    float2 lbv = ((const float2*)lb)[lane];
    float y0 = fmaxf((acc.x - mean) * rstd * lgv.x + lbv.x, 0.0f);
    float y1 = fmaxf((acc.y - mean) * rstd * lgv.y + lbv.y, 0.0f);
    float2 xo = ((const float2*)xold)[(size_t)n * 64 + lane];
    float o0 = xo.x + y0, o1 = xo.y + y1;
    ((float2*)xnew)[(size_t)n * 64 + lane] = make_float2(o0, o1);
    xnewb[(size_t)n * 64 + lane] = f2bf_pack(o0, o1);
}

extern "C" void kernel_launch(void* const* d_in, const int* in_sizes, int n_in,
                              void* d_out, int out_size, void* d_ws,
                              size_t ws_size, hipStream_t stream) {
    const float* x = (const float*)d_in[0];
    const float* motif = (const float*)d_in[1];
    const void* ei = d_in[2];
    const float* gw1 = (const float*)d_in[3];
    const float* gb1 = (const float*)d_in[4];
    const float* gw2 = (const float*)d_in[5];
    const float* gb2 = (const float*)d_in[6];
    const float* cw = (const float*)d_in[7];   // [2,128,128]
    const float* cb = (const float*)d_in[8];   // [2,128]
    const float* lg = (const float*)d_in[9];
    const float* lb = (const float*)d_in[10];
    const float* hw = (const float*)d_in[11];  // [128,64]
    const float* hb = (const float*)d_in[12];
    float* out = (float*)d_out;

    float* ws = (float*)d_ws;
    size_t o = 0;
    float* dinv = ws + o; o += NN;
    int* flag = (int*)(ws + o); o += 64;
    int* count = (int*)(ws + o); o += NN;
    int* rowstart = (int*)(ws + o); o += NN;
    int* cursor = (int*)(ws + o); o += NN;
    int* bsum = (int*)(ws + o); o += 64;
    int* boffs = (int*)(ws + o); o += 64;
    int2* es = (int2*)(ws + o); o += 2 * (size_t)NE;
    float* g_s = ws + o; o += NE;
    unsigned* xwb = (unsigned*)(ws + o); o += (size_t)NN * 64;  // bf16 xw, aliases Pab
    float* xc = ws + o; o += (size_t)NN * IND;
    unsigned* xb = (unsigned*)(ws + o); o += (size_t)NN * 64;   // bf16 x
    unsigned* xcb = (unsigned*)(ws + o); o += (size_t)NN * 64;  // bf16 xc
    unsigned* btf = (unsigned*)(ws + o); o += 20480;            // frag-packed W

    unsigned* Pab = xwb;  // alias: Pab dead before first k_mm_conv writes xwb

    k_detect<<<1, 64, 0, stream>>>(ei, flag);
    k_init<<<(NN + 255) / 256, 256, 0, stream>>>(count);
    k_hist<<<NE / 256, 256, 0, stream>>>(ei, flag, count);
    k_cvt<<<(NN * 32 + 255) / 256, 256, 0, stream>>>(x, xb);
    k_prep<<<80, 256, 0, stream>>>(cw, hw, btf);
    k_pre<<<(NN + 63) / 64, 256, 0, stream>>>(motif, gw1, Pab);

    // counting sort by dst -> CSR (shared by both layers)
    k_scan1<<<(NN + 2047) / 2048, 256, 0, stream>>>(count, rowstart, bsum);
    k_scan2<<<1, 64, 0, stream>>>(bsum, boffs);
    k_scan3<<<(NN + 255) / 256, 256, 0, stream>>>(rowstart, boffs, cursor);
    // XCD-partitioned fill: 8 partitions x ceil(NE/2048) chunks
    k_fill<<<8 * ((NE + 2047) / 2048), 256, 0, stream>>>(ei, flag, cursor, es);

    // gate in dst-sorted order, then deg, then normalize weights in place
    k_gate<<<NE / 256, 256, 0, stream>>>(motif, es, Pab, gw1, gb1, gw2, gb2,
                                         g_s);
    k_deg<<<(NN + 3) / 4, 256, 0, stream>>>(rowstart, count, g_s, dinv);
    k_wnorm<<<NE / 256, 256, 0, stream>>>(es, dinv, g_s);

    const int gmm = (NN + 63) / 64;
    // layer 0
    k_mm_conv<<<gmm, 256, 0, stream>>>((const ushort_t*)xb, (const uint4*)btf,
                                       (ushort_t*)xwb);
    k_aggr<<<(NN + 3) / 4, 256, 0, stream>>>(rowstart, count, es, g_s, xwb,
                                             dinv, x, xc, xcb, cb, lg, lb);
    // layer 1
    k_mm_conv<<<gmm, 256, 0, stream>>>((const ushort_t*)xcb,
                                       (const uint4*)(btf + 8192),
                                       (ushort_t*)xwb);
    k_aggr<<<(NN + 3) / 4, 256, 0, stream>>>(rowstart, count, es, g_s, xwb,
                                             dinv, xc, xc, xcb, cb + IND,
                                             lg + IND, lb + IND);

    k_mm_head<<<gmm, 256, 0, stream>>>((const ushort_t*)xcb,
                                       (const uint4*)(btf + 16384), hb, out);
}

// Round 10
// 551.501 us; speedup vs baseline: 2.0365x; 1.1330x over previous
//
#include <hip/hip_runtime.h>
#include <cstdint>
#include <cstddef>

#define NN 100000
#define NE 1600000
#define IND 128
#define OUTD 64
#define MDIM 16
#define GHID 64
#define NPART 12500  // NN / 8 XCDs

typedef __attribute__((ext_vector_type(8))) short bf8_t;
typedef __attribute__((ext_vector_type(4))) float f4_t;
typedef unsigned short ushort_t;

// ---- bf16 helpers (RNE pack, exact unpack) --------------------------------
__device__ inline unsigned f2bf_pack(float a, float b) {
    unsigned ua = __float_as_uint(a);
    unsigned ub = __float_as_uint(b);
    unsigned ra = (ua + 0x7fffu + ((ua >> 16) & 1u)) >> 16;
    unsigned rb = (ub + 0x7fffu + ((ub >> 16) & 1u)) >> 16;
    return ra | (rb << 16);
}
__device__ inline ushort_t f2bf1(float f) {
    unsigned u = __float_as_uint(f);
    return (ushort_t)((u + 0x7fffu + ((u >> 16) & 1u)) >> 16);
}
__device__ inline float2 bf2x(unsigned u) {
    return make_float2(__uint_as_float(u << 16),
                       __uint_as_float(u & 0xffff0000u));
}

// ---------------- edge-index dtype detection (int32 vs int64) --------------
__global__ __launch_bounds__(64) void k_detect(const void* ei, int* flag) {
    const unsigned long long* p = (const unsigned long long*)ei;
    int i = threadIdx.x;
    unsigned long long v = p[(size_t)i * (NE / 64)];
    bool hi0 = (v >> 32) == 0ull;
    unsigned long long b = __ballot(hi0);
    if (i == 0) *flag = (b == ~0ull) ? 1 : 0;  // all high dwords zero -> int64
}

__global__ __launch_bounds__(256) void k_init(int* count) {
    int n = blockIdx.x * 256 + threadIdx.x;
    if (n < NN) count[n] = 0;
}

// ---------------- dst histogram straight from raw ei -----------------------
__global__ __launch_bounds__(256) void k_hist(const void* __restrict__ ei,
                                              const int* __restrict__ flag,
                                              int* __restrict__ count) {
    int e = blockIdx.x * 256 + threadIdx.x;
    if (e >= NE) return;
    int d = (*flag) ? (int)((const long long*)ei)[NE + e]
                    : ((const int*)ei)[NE + e];
    atomicAdd(&count[d], 1);
}

// ---------------- pack conv/head/gate weights into MFMA B-fragment order ---
// btf layout (uints):
//   [0,8192)       conv L0: 8nt x 4kk x 64lane x 4
//   [8192,16384)   conv L1
//   [16384,20480)  head:    4nt x 4kk x 64lane x 4
//   [20480,22528)  gate W1: 4nt x 2kk x 64lane x 4 (64x64, K=64)
// frag elem j: B[k = kk*32 + (lane>>4)*8 + j][n = nt*16 + (lane&15)]
__global__ __launch_bounds__(256) void k_prep(const float* __restrict__ cw,
                                              const float* __restrict__ hw,
                                              const float* __restrict__ w1,
                                              unsigned* __restrict__ btf) {
    int i = blockIdx.x * 256 + threadIdx.x;
    if (i >= 22528) return;
    const float* W;
    int ncols, local, kk, nt;
    int w, lane;
    if (i < 16384) {
        W = cw + (i >> 13) * 16384; ncols = 128; local = i & 8191;
        w = local & 3; lane = (local >> 2) & 63;
        kk = (local >> 8) & 3; nt = local >> 10;
    } else if (i < 20480) {
        W = hw; ncols = 64; local = i - 16384;
        w = local & 3; lane = (local >> 2) & 63;
        kk = (local >> 8) & 3; nt = local >> 10;
    } else {
        W = w1; ncols = 64; local = i - 20480;
        w = local & 3; lane = (local >> 2) & 63;
        kk = (local >> 8) & 1; nt = local >> 9;
    }
    int n = nt * 16 + (lane & 15);
    int k = kk * 32 + (lane >> 4) * 8 + 2 * w;
    btf[i] = f2bf_pack(W[k * ncols + n], W[(k + 1) * ncols + n]);
}

// ---------------- counting-sort scan (exclusive prefix of count) -----------
__global__ __launch_bounds__(256) void k_scan1(const int* __restrict__ count,
                                               int* __restrict__ rs,
                                               int* __restrict__ bsum) {
    __shared__ int sd[256];
    int tid = threadIdx.x;
    int base = blockIdx.x * 2048 + tid * 8;
    int loc[8]; int s = 0;
#pragma unroll
    for (int i = 0; i < 8; i++) {
        int idx = base + i;
        int v = (idx < NN) ? count[idx] : 0;
        loc[i] = s; s += v;
    }
    sd[tid] = s; __syncthreads();
    for (int off = 1; off < 256; off <<= 1) {
        int t = (tid >= off) ? sd[tid - off] : 0;
        __syncthreads();
        sd[tid] += t;
        __syncthreads();
    }
    int texcl = sd[tid] - s;
    if (tid == 255) bsum[blockIdx.x] = sd[255];
#pragma unroll
    for (int i = 0; i < 8; i++) {
        int idx = base + i;
        if (idx < NN) rs[idx] = texcl + loc[i];
    }
}

__global__ __launch_bounds__(64) void k_scan2(const int* __restrict__ bsum,
                                              int* __restrict__ boffs) {
    int tid = threadIdx.x;
    int v = (tid < 49) ? bsum[tid] : 0;
    int x = v;
#pragma unroll
    for (int off = 1; off < 64; off <<= 1) {
        int t = __shfl_up(x, off, 64);
        if (tid >= off) x += t;
    }
    boffs[tid] = x - v;  // exclusive
}

__global__ __launch_bounds__(256) void k_scan3(int* __restrict__ rs,
                                               const int* __restrict__ boffs,
                                               int* __restrict__ cursor) {
    int i = blockIdx.x * 256 + threadIdx.x;
    if (i < NN) {
        int v = rs[i] + boffs[i >> 11];
        rs[i] = v;
        cursor[i] = v;
    }
}

// ---------------- fill CSR, XCD-partitioned by dst range -------------------
__global__ __launch_bounds__(256) void k_fill(const void* __restrict__ ei,
                                              const int* __restrict__ flag,
                                              int* __restrict__ cursor,
                                              int2* __restrict__ es) {
    int p = blockIdx.x & 7;
    int base = (blockIdx.x >> 3) * 2048;
    bool is64 = (*flag) != 0;
#pragma unroll 1
    for (int it = 0; it < 8; it++) {
        int e = base + it * 256 + threadIdx.x;
        if (e >= NE) break;
        int d = is64 ? (int)((const long long*)ei)[NE + e]
                     : ((const int*)ei)[NE + e];
        if ((unsigned)d / NPART != (unsigned)p) continue;
        int s = is64 ? (int)((const long long*)ei)[e] : ((const int*)ei)[e];
        int pos = atomicAdd(&cursor[d], 1);
        es[pos] = make_int2(s, d);
    }
}

// ---------------- edge gate via MFMA: h = [mu|mv|f2|f3] @ W1 + b1 ----------
// One wave = 16 edges. Lane (quad,lx): loads motif[ s|d (quad<2?s:d) ]
// half-row (quad&1) for edge e0+lx = exactly the kk=0 A-frag slice;
// shfl_xor(.,32) swaps mu<->mv halves to build f2/f3 = kk=1 slice.
// C-init = b1. Epilogue: relu dot w2 + shfl-reduce over lx, sigmoid.
__global__ __launch_bounds__(256) void k_gate(
    const float* __restrict__ motif, const int2* __restrict__ es,
    const uint4* __restrict__ w1f, const float* __restrict__ b1,
    const float* __restrict__ w2, const float* __restrict__ b2,
    float* __restrict__ g_s) {
    int wv = threadIdx.x >> 6, lane = threadIdx.x & 63;
    int e0 = (blockIdx.x * 4 + wv) * 16;
    int quad = lane >> 4, lx = lane & 15;
    int2 sd = es[e0 + lx];
    int node = (quad < 2) ? sd.x : sd.y;
    int half = quad & 1;
    const float4* mp =
        (const float4*)(motif + (size_t)node * MDIM + half * 8);
    float4 v0 = mp[0], v1 = mp[1];
    float own[8] = {v0.x, v0.y, v0.z, v0.w, v1.x, v1.y, v1.z, v1.w};
    union { unsigned u[4]; bf8_t v; } a0, a1;
#pragma unroll
    for (int q = 0; q < 4; q++) a0.u[q] = f2bf_pack(own[2 * q], own[2 * q + 1]);
    float f[8];
#pragma unroll
    for (int j = 0; j < 8; j++) {
        float oth = __shfl_xor(own[j], 32, 64);
        f[j] = (quad < 2) ? fabsf(own[j] - oth) : own[j] * oth;
    }
#pragma unroll
    for (int q = 0; q < 4; q++) a1.u[q] = f2bf_pack(f[2 * q], f[2 * q + 1]);
    f4_t acc[4];
#pragma unroll
    for (int nt = 0; nt < 4; nt++) {
        float bi = b1[nt * 16 + lx];
        acc[nt] = (f4_t){bi, bi, bi, bi};
    }
#pragma unroll
    for (int nt = 0; nt < 4; nt++) {
        union { uint4 u; bf8_t v; } b0, bb1;
        b0.u = w1f[(nt * 2 + 0) * 64 + lane];
        bb1.u = w1f[(nt * 2 + 1) * 64 + lane];
        acc[nt] = __builtin_amdgcn_mfma_f32_16x16x32_bf16(a0.v, b0.v, acc[nt],
                                                          0, 0, 0);
        acc[nt] = __builtin_amdgcn_mfma_f32_16x16x32_bf16(a1.v, bb1.v, acc[nt],
                                                          0, 0, 0);
    }
    float p[4] = {0.f, 0.f, 0.f, 0.f};
#pragma unroll
    for (int nt = 0; nt < 4; nt++) {
        float w2v = w2[nt * 16 + lx];
#pragma unroll
        for (int r = 0; r < 4; r++)
            p[r] = fmaf(fmaxf(acc[nt][r], 0.0f), w2v, p[r]);
    }
#pragma unroll
    for (int m = 1; m < 16; m <<= 1) {
#pragma unroll
        for (int r = 0; r < 4; r++) p[r] += __shfl_xor(p[r], m, 64);
    }
    if (lx < 4) {
        float g = p[lx] + b2[0];
        g_s[e0 + quad * 4 + lx] = 1.0f / (1.0f + __expf(-g));
    }
}

// ---------------- deg = 1 + row-sum of sorted gates -> dinv (wave/node) ----
__global__ __launch_bounds__(256) void k_deg(const int* __restrict__ rowstart,
                                             const int* __restrict__ count,
                                             const float* __restrict__ g_s,
                                             float* __restrict__ dinv) {
    int n = blockIdx.x * 4 + (threadIdx.x >> 6);
    int lane = threadIdx.x & 63;
    if (n >= NN) return;
    int a = rowstart[n], cnt = count[n];
    float sum = 0.0f;
    for (int c = lane; c < cnt; c += 64) sum += g_s[a + c];
#pragma unroll
    for (int m = 1; m < 64; m <<= 1) sum += __shfl_xor(sum, m, 64);
    if (lane == 0) dinv[n] = rsqrtf(1.0f + sum);
}

// ---------------- g_s[e] *= dinv[src]*dinv[dst] (in-place, coalesced) ------
__global__ __launch_bounds__(256) void k_wnorm(const int2* __restrict__ es,
                                               const float* __restrict__ dinv,
                                               float* __restrict__ g_s) {
    int e = blockIdx.x * 256 + threadIdx.x;
    if (e >= NE) return;
    int2 sd = es[e];
    g_s[e] *= dinv[sd.x] * dinv[sd.y];
}

// ---------------- MFMA GEMM (layer 0): xw_bf16 = round_bf16(x_f32) @ W -----
__global__ __launch_bounds__(256) void k_mm_conv_f32(
    const float* __restrict__ A, const uint4* __restrict__ btf,
    ushort_t* __restrict__ outb) {
    int w = threadIdx.x >> 6, lane = threadIdx.x & 63;
    int mh = w & 1, nh = w >> 1;
    int quad = lane >> 4, lx = lane & 15;
    int m0 = blockIdx.x * 64 + mh * 32;
    bf8_t a[2][4];
#pragma unroll
    for (int mt = 0; mt < 2; mt++) {
        int row = m0 + mt * 16 + lx;
        row = row < NN ? row : NN - 1;
#pragma unroll
        for (int kk = 0; kk < 4; kk++) {
            const float4* ap =
                (const float4*)(A + (size_t)row * 128 + kk * 32 + quad * 8);
            float4 u0 = ap[0], u1 = ap[1];
            union { unsigned u[4]; bf8_t v; } t;
            t.u[0] = f2bf_pack(u0.x, u0.y);
            t.u[1] = f2bf_pack(u0.z, u0.w);
            t.u[2] = f2bf_pack(u1.x, u1.y);
            t.u[3] = f2bf_pack(u1.z, u1.w);
            a[mt][kk] = t.v;
        }
    }
    f4_t acc[2][4];
#pragma unroll
    for (int mt = 0; mt < 2; mt++)
#pragma unroll
        for (int nt = 0; nt < 4; nt++) acc[mt][nt] = (f4_t){0.f, 0.f, 0.f, 0.f};
#pragma unroll
    for (int nt = 0; nt < 4; nt++) {
        int ntg = nh * 4 + nt;
#pragma unroll
        for (int kk = 0; kk < 4; kk++) {
            union { uint4 u; bf8_t v; } bb;
            bb.u = btf[(ntg * 4 + kk) * 64 + lane];
            acc[0][nt] = __builtin_amdgcn_mfma_f32_16x16x32_bf16(
                a[0][kk], bb.v, acc[0][nt], 0, 0, 0);
            acc[1][nt] = __builtin_amdgcn_mfma_f32_16x16x32_bf16(
                a[1][kk], bb.v, acc[1][nt], 0, 0, 0);
        }
    }
#pragma unroll
    for (int mt = 0; mt < 2; mt++)
#pragma unroll
        for (int nt = 0; nt < 4; nt++) {
#pragma unroll
            for (int r = 0; r < 4; r++) {
                int row = m0 + mt * 16 + quad * 4 + r;
                if (row < NN)
                    outb[(size_t)row * 128 + (nh * 4 + nt) * 16 + lx] =
                        f2bf1(acc[mt][nt][r]);
            }
        }
}

// ---------------- MFMA GEMM (layer 1): xw_bf16 = A_bf16 @ W ----------------
__global__ __launch_bounds__(256) void k_mm_conv(
    const ushort_t* __restrict__ A, const uint4* __restrict__ btf,
    ushort_t* __restrict__ outb) {
    int w = threadIdx.x >> 6, lane = threadIdx.x & 63;
    int mh = w & 1, nh = w >> 1;
    int quad = lane >> 4, lx = lane & 15;
    int m0 = blockIdx.x * 64 + mh * 32;
    bf8_t a[2][4];
#pragma unroll
    for (int mt = 0; mt < 2; mt++) {
        int row = m0 + mt * 16 + lx;
        row = row < NN ? row : NN - 1;
#pragma unroll
        for (int kk = 0; kk < 4; kk++)
            a[mt][kk] = *(const bf8_t*)(A + (size_t)row * 128 + kk * 32 + quad * 8);
    }
    f4_t acc[2][4];
#pragma unroll
    for (int mt = 0; mt < 2; mt++)
#pragma unroll
        for (int nt = 0; nt < 4; nt++) acc[mt][nt] = (f4_t){0.f, 0.f, 0.f, 0.f};
#pragma unroll
    for (int nt = 0; nt < 4; nt++) {
        int ntg = nh * 4 + nt;
#pragma unroll
        for (int kk = 0; kk < 4; kk++) {
            union { uint4 u; bf8_t v; } bb;
            bb.u = btf[(ntg * 4 + kk) * 64 + lane];
            acc[0][nt] = __builtin_amdgcn_mfma_f32_16x16x32_bf16(
                a[0][kk], bb.v, acc[0][nt], 0, 0, 0);
            acc[1][nt] = __builtin_amdgcn_mfma_f32_16x16x32_bf16(
                a[1][kk], bb.v, acc[1][nt], 0, 0, 0);
        }
    }
#pragma unroll
    for (int mt = 0; mt < 2; mt++)
#pragma unroll
        for (int nt = 0; nt < 4; nt++) {
#pragma unroll
            for (int r = 0; r < 4; r++) {
                int row = m0 + mt * 16 + quad * 4 + r;
                if (row < NN)
                    outb[(size_t)row * 128 + (nh * 4 + nt) * 16 + lx] =
                        f2bf1(acc[mt][nt][r]);
            }
        }
}

// ---------------- MFMA GEMM head: out = A_bf16 @ head_w + head_b (N=64) ----
__global__ __launch_bounds__(256) void k_mm_head(
    const ushort_t* __restrict__ A, const uint4* __restrict__ btf,
    const float* __restrict__ bias, float* __restrict__ out) {
    int w = threadIdx.x >> 6, lane = threadIdx.x & 63;
    int mh = w & 1, nh = w >> 1;
    int quad = lane >> 4, lx = lane & 15;
    int m0 = blockIdx.x * 64 + mh * 32;
    bf8_t a[2][4];
#pragma unroll
    for (int mt = 0; mt < 2; mt++) {
        int row = m0 + mt * 16 + lx;
        row = row < NN ? row : NN - 1;
#pragma unroll
        for (int kk = 0; kk < 4; kk++)
            a[mt][kk] = *(const bf8_t*)(A + (size_t)row * 128 + kk * 32 + quad * 8);
    }
    f4_t acc[2][2];
#pragma unroll
    for (int mt = 0; mt < 2; mt++)
#pragma unroll
        for (int nt = 0; nt < 2; nt++) acc[mt][nt] = (f4_t){0.f, 0.f, 0.f, 0.f};
#pragma unroll
    for (int nt = 0; nt < 2; nt++) {
        int ntg = nh * 2 + nt;
#pragma unroll
        for (int kk = 0; kk < 4; kk++) {
            union { uint4 u; bf8_t v; } bb;
            bb.u = btf[(ntg * 4 + kk) * 64 + lane];
            acc[0][nt] = __builtin_amdgcn_mfma_f32_16x16x32_bf16(
                a[0][kk], bb.v, acc[0][nt], 0, 0, 0);
            acc[1][nt] = __builtin_amdgcn_mfma_f32_16x16x32_bf16(
                a[1][kk], bb.v, acc[1][nt], 0, 0, 0);
        }
    }
#pragma unroll
    for (int mt = 0; mt < 2; mt++)
#pragma unroll
        for (int nt = 0; nt < 2; nt++) {
            int col = (nh * 2 + nt) * 16 + lx;
            float bs = bias[col];
#pragma unroll
            for (int r = 0; r < 4; r++) {
                int row = m0 + mt * 16 + quad * 4 + r;
                if (row < NN) out[(size_t)row * 64 + col] = acc[mt][nt][r] + bs;
            }
        }
}

// ---------------- fused gather(bf16) + bias + LN + relu + residual ---------
__global__ __launch_bounds__(256) void k_aggr(
    const int* __restrict__ rowstart, const int* __restrict__ count,
    const int2* __restrict__ es, const float* __restrict__ w_s,
    const unsigned* __restrict__ xwb, const float* __restrict__ dinv,
    const float* __restrict__ xold, float* __restrict__ xnew,
    unsigned* __restrict__ xnewb, const float* __restrict__ cb,
    const float* __restrict__ lg, const float* __restrict__ lb) {
    int n = blockIdx.x * 4 + (threadIdx.x >> 6);
    int lane = threadIdx.x & 63;
    if (n >= NN) return;
    float dn = dinv[n];
    float2 acc = bf2x(xwb[(size_t)n * 64 + lane]);  // self-loop
    acc.x *= dn * dn; acc.y *= dn * dn;
    int start = rowstart[n], cnt = count[n];
    for (int c = 0; c < cnt; c += 64) {
        int rem = cnt - c;
        int sv = 0; float wv = 0.0f;
        if (lane < rem) {
            sv = es[start + c + lane].x;
            wv = w_s[start + c + lane];
        }
        int m = rem < 64 ? rem : 64;
        int j = 0;
        for (; j + 4 <= m; j += 4) {  // 4 independent loads in flight
            int s0 = __shfl(sv, j, 64), s1 = __shfl(sv, j + 1, 64);
            int s2 = __shfl(sv, j + 2, 64), s3 = __shfl(sv, j + 3, 64);
            float w0 = __shfl(wv, j, 64), w1 = __shfl(wv, j + 1, 64);
            float w2 = __shfl(wv, j + 2, 64), w3 = __shfl(wv, j + 3, 64);
            unsigned u0 = xwb[(size_t)s0 * 64 + lane];
            unsigned u1 = xwb[(size_t)s1 * 64 + lane];
            unsigned u2 = xwb[(size_t)s2 * 64 + lane];
            unsigned u3 = xwb[(size_t)s3 * 64 + lane];
            float2 v0 = bf2x(u0), v1 = bf2x(u1), v2 = bf2x(u2), v3 = bf2x(u3);
            acc.x = fmaf(w0, v0.x, acc.x); acc.y = fmaf(w0, v0.y, acc.y);
            acc.x = fmaf(w1, v1.x, acc.x); acc.y = fmaf(w1, v1.y, acc.y);
            acc.x = fmaf(w2, v2.x, acc.x); acc.y = fmaf(w2, v2.y, acc.y);
            acc.x = fmaf(w3, v3.x, acc.x); acc.y = fmaf(w3, v3.y, acc.y);
        }
        for (; j < m; j++) {
            int s = __shfl(sv, j, 64);
            float w = __shfl(wv, j, 64);
            float2 v = bf2x(xwb[(size_t)s * 64 + lane]);
            acc.x = fmaf(w, v.x, acc.x); acc.y = fmaf(w, v.y, acc.y);
        }
    }
    float2 cbv = ((const float2*)cb)[lane];
    acc.x += cbv.x; acc.y += cbv.y;
    float s1 = acc.x + acc.y, s2 = acc.x * acc.x + acc.y * acc.y;
#pragma unroll
    for (int mm = 1; mm < 64; mm <<= 1) {
        s1 += __shfl_xor(s1, mm, 64);
        s2 += __shfl_xor(s2, mm, 64);
    }
    float mean = s1 * (1.0f / 128.0f);
    float var = s2 * (1.0f / 128.0f) - mean * mean;
    float rstd = rsqrtf(var + 1e-5f);
    float2 lgv = ((const float2*)lg)[lane];
    float2 lbv = ((const float2*)lb)[lane];
    float y0 = fmaxf((acc.x - mean) * rstd * lgv.x + lbv.x, 0.0f);
    float y1 = fmaxf((acc.y - mean) * rstd * lgv.y + lbv.y, 0.0f);
    float2 xo = ((const float2*)xold)[(size_t)n * 64 + lane];
    float o0 = xo.x + y0, o1 = xo.y + y1;
    ((float2*)xnew)[(size_t)n * 64 + lane] = make_float2(o0, o1);
    xnewb[(size_t)n * 64 + lane] = f2bf_pack(o0, o1);
}

extern "C" void kernel_launch(void* const* d_in, const int* in_sizes, int n_in,
                              void* d_out, int out_size, void* d_ws,
                              size_t ws_size, hipStream_t stream) {
    const float* x = (const float*)d_in[0];
    const float* motif = (const float*)d_in[1];
    const void* ei = d_in[2];
    const float* gw1 = (const float*)d_in[3];
    const float* gb1 = (const float*)d_in[4];
    const float* gw2 = (const float*)d_in[5];
    const float* gb2 = (const float*)d_in[6];
    const float* cw = (const float*)d_in[7];   // [2,128,128]
    const float* cb = (const float*)d_in[8];   // [2,128]
    const float* lg = (const float*)d_in[9];
    const float* lb = (const float*)d_in[10];
    const float* hw = (const float*)d_in[11];  // [128,64]
    const float* hb = (const float*)d_in[12];
    float* out = (float*)d_out;

    float* ws = (float*)d_ws;
    size_t o = 0;
    float* dinv = ws + o; o += NN;
    int* flag = (int*)(ws + o); o += 64;
    int* count = (int*)(ws + o); o += NN;
    int* rowstart = (int*)(ws + o); o += NN;
    int* cursor = (int*)(ws + o); o += NN;
    int* bsum = (int*)(ws + o); o += 64;
    int* boffs = (int*)(ws + o); o += 64;
    int2* es = (int2*)(ws + o); o += 2 * (size_t)NE;
    float* g_s = ws + o; o += NE;
    unsigned* xwb = (unsigned*)(ws + o); o += (size_t)NN * 64;  // bf16 xw
    float* xc = ws + o; o += (size_t)NN * IND;
    unsigned* xcb = (unsigned*)(ws + o); o += (size_t)NN * 64;  // bf16 xc
    unsigned* btf = (unsigned*)(ws + o); o += 22528;            // frag-packed W

    k_detect<<<1, 64, 0, stream>>>(ei, flag);
    k_init<<<(NN + 255) / 256, 256, 0, stream>>>(count);
    k_hist<<<NE / 256, 256, 0, stream>>>(ei, flag, count);
    k_prep<<<88, 256, 0, stream>>>(cw, hw, gw1, btf);

    // counting sort by dst -> CSR (shared by both layers)
    k_scan1<<<(NN + 2047) / 2048, 256, 0, stream>>>(count, rowstart, bsum);
    k_scan2<<<1, 64, 0, stream>>>(bsum, boffs);
    k_scan3<<<(NN + 255) / 256, 256, 0, stream>>>(rowstart, boffs, cursor);
    // XCD-partitioned fill: 8 partitions x ceil(NE/2048) chunks
    k_fill<<<8 * ((NE + 2047) / 2048), 256, 0, stream>>>(ei, flag, cursor, es);

    // gate (MFMA over 16-edge waves, dst-sorted), deg, normalize in place
    k_gate<<<NE / 64, 256, 0, stream>>>(motif, es, (const uint4*)(btf + 20480),
                                        gb1, gw2, gb2, g_s);
    k_deg<<<(NN + 3) / 4, 256, 0, stream>>>(rowstart, count, g_s, dinv);
    k_wnorm<<<NE / 256, 256, 0, stream>>>(es, dinv, g_s);

    const int gmm = (NN + 63) / 64;
    // layer 0 (reads fp32 x directly, rounds to bf16 in-kernel)
    k_mm_conv_f32<<<gmm, 256, 0, stream>>>(x, (const uint4*)btf,
                                           (ushort_t*)xwb);
    k_aggr<<<(NN + 3) / 4, 256, 0, stream>>>(rowstart, count, es, g_s, xwb,
                                             dinv, x, xc, xcb, cb, lg, lb);
    // layer 1
    k_mm_conv<<<gmm, 256, 0, stream>>>((const ushort_t*)xcb,
                                       (const uint4*)(btf + 8192),
                                       (ushort_t*)xwb);
    k_aggr<<<(NN + 3) / 4, 256, 0, stream>>>(rowstart, count, es, g_s, xwb,
                                             dinv, xc, xc, xcb, cb + IND,
                                             lg + IND, lb + IND);

    k_mm_head<<<gmm, 256, 0, stream>>>((const ushort_t*)xcb,
                                       (const uint4*)(btf + 16384), hb, out);
}